// Round 3
// baseline (10959.930 us; speedup 1.0000x reference)
//
#include <hip/hip_runtime.h>
#include <math.h>

#define B_SZ 128
#define T_SZ 256
#define DIN  128
#define HID  256
#define H2   512
#define NCLS 250

// ---------------- per-group barrier (16 WGs, agent scope, hardened) --------
// cnt at +0, gen at +16 words (64B apart); 256B per group block.
__device__ __forceinline__ void group_barrier(unsigned* cnt, unsigned* gen) {
    __syncthreads();  // all waves of this WG done; stores issued (vmcnt drain)
    if (threadIdx.x == 0) {
        // make this WG's global stores visible agent-wide (L2 writeback)
        __builtin_amdgcn_fence(__ATOMIC_RELEASE, "agent");
        unsigned g = __hip_atomic_load(gen, __ATOMIC_RELAXED, __HIP_MEMORY_SCOPE_AGENT);
        unsigned prev = __hip_atomic_fetch_add(cnt, 1u, __ATOMIC_ACQ_REL, __HIP_MEMORY_SCOPE_AGENT);
        if (prev == 15u) {
            __hip_atomic_store(cnt, 0u, __ATOMIC_RELAXED, __HIP_MEMORY_SCOPE_AGENT);
            __hip_atomic_fetch_add(gen, 1u, __ATOMIC_RELEASE, __HIP_MEMORY_SCOPE_AGENT);
        } else {
            while (__hip_atomic_load(gen, __ATOMIC_RELAXED, __HIP_MEMORY_SCOPE_AGENT) == g)
                __builtin_amdgcn_s_sleep(1);
        }
        // invalidate stale L1/L2 lines before anyone re-reads h (both paths)
        __builtin_amdgcn_fence(__ATOMIC_ACQUIRE, "agent");
    }
    __syncthreads();
}

#define ACC4(A, Wp, v) \
    A = fmaf((v).x, (Wp)[0], A); A = fmaf((v).y, (Wp)[1], A); \
    A = fmaf((v).z, (Wp)[2], A); A = fmaf((v).w, (Wp)[3], A)

// ---------------- L0: both dirs, fused x-GEMM, persistent scan --------------
// grid 256 = dir(2) x bt(8 tiles of 16 rows) x hct(16 tiles of 16 cols).
// Group = (dir,bt) = wg>>4: 16 groups x 16 WGs. Thread (hc,ks): 16-way k-split.
__global__ __launch_bounds__(256, 2) void l0_scan(
    const float* __restrict__ x,
    const float* __restrict__ wihf, const float* __restrict__ bihf,
    const float* __restrict__ whhf, const float* __restrict__ bhhf,
    const float* __restrict__ wihb, const float* __restrict__ bihb,
    const float* __restrict__ whhb, const float* __restrict__ bhhb,
    float* __restrict__ hbuf,   // [2 dir][2 par][B][HID]
    float* __restrict__ h1,     // [B][T][512]
    unsigned* __restrict__ bar)
{
    __shared__ float hlds[16][256];
    __shared__ float xlds[16][128];
    const int tid = threadIdx.x;
    const int wg  = blockIdx.x;
    const int dir = wg >> 7;
    const int rem = wg & 127;
    const int b0  = (rem >> 4) * 16;
    const int hct = rem & 15;
    const int hc = tid >> 4, ks = tid & 15, ks4 = ks * 4;
    const int hcg = hct * 16 + hc;
    unsigned* cnt = bar + (wg >> 4) * 64;
    unsigned* gen = cnt + 16;

    const float* wih = dir ? wihb : wihf;
    const float* bih = dir ? bihb : bihf;
    const float* whh = dir ? whhb : whhf;
    const float* bhh = dir ? bhhb : bhhf;

    float Wr[3][16], Wx[3][8];
#pragma unroll
    for (int g = 0; g < 3; ++g) {
#pragma unroll
        for (int j = 0; j < 4; ++j) {
            float4 wv = *(const float4*)(whh + (size_t)(g * HID + hcg) * HID + j * 64 + ks4);
            Wr[g][4 * j] = wv.x; Wr[g][4 * j + 1] = wv.y; Wr[g][4 * j + 2] = wv.z; Wr[g][4 * j + 3] = wv.w;
        }
#pragma unroll
        for (int j = 0; j < 2; ++j) {
            float4 wv = *(const float4*)(wih + (size_t)(g * HID + hcg) * DIN + j * 64 + ks4);
            Wx[g][4 * j] = wv.x; Wx[g][4 * j + 1] = wv.y; Wx[g][4 * j + 2] = wv.z; Wx[g][4 * j + 3] = wv.w;
        }
    }
    const float sbr = bih[hcg] + bhh[hcg];
    const float sbz = bih[HID + hcg] + bhh[HID + hcg];
    const float bxn = bih[2 * HID + hcg];
    const float bhn = bhh[2 * HID + hcg];

    float* hb = hbuf + (size_t)dir * 2 * B_SZ * HID;
    const int r8 = tid >> 5, c32 = (tid & 31) * 4;

    for (int t = 0; t < T_SZ; ++t) {
        const int tg = dir ? (T_SZ - 1 - t) : t;
        const float* hprev = hb + (size_t)(t & 1) * B_SZ * HID;
        float* hnext       = hb + (size_t)((t + 1) & 1) * B_SZ * HID;

#pragma unroll
        for (int p = 0; p < 2; ++p) {
            const int row = p * 8 + r8;
            *(float4*)&xlds[row][c32] =
                *(const float4*)(x + ((size_t)(b0 + row) * T_SZ + tg) * DIN + c32);
            const float* hsrc = hprev + (size_t)(b0 + row) * HID;
            *(float4*)&hlds[row][c32]       = *(const float4*)(hsrc + c32);
            *(float4*)&hlds[row][128 + c32] = *(const float4*)(hsrc + 128 + c32);
        }
        __syncthreads();

        float aR[16], aZ[16], aH[16], aX[16];
#pragma unroll
        for (int b = 0; b < 16; ++b) { aR[b] = 0.f; aZ[b] = 0.f; aH[b] = 0.f; aX[b] = 0.f; }
#pragma unroll
        for (int b = 0; b < 16; ++b) {
#pragma unroll
            for (int j = 0; j < 4; ++j) {
                float4 hv = *(const float4*)&hlds[b][j * 64 + ks4];
                ACC4(aR[b], &Wr[0][4 * j], hv);
                ACC4(aZ[b], &Wr[1][4 * j], hv);
                ACC4(aH[b], &Wr[2][4 * j], hv);
            }
#pragma unroll
            for (int j = 0; j < 2; ++j) {
                float4 xv = *(const float4*)&xlds[b][j * 64 + ks4];
                ACC4(aR[b], &Wx[0][4 * j], xv);
                ACC4(aZ[b], &Wx[1][4 * j], xv);
                ACC4(aX[b], &Wx[2][4 * j], xv);
            }
        }
#pragma unroll
        for (int m = 1; m <= 8; m <<= 1)
#pragma unroll
            for (int b = 0; b < 16; ++b) {
                aR[b] += __shfl_xor(aR[b], m, 64);
                aZ[b] += __shfl_xor(aZ[b], m, 64);
                aH[b] += __shfl_xor(aH[b], m, 64);
                aX[b] += __shfl_xor(aX[b], m, 64);
            }

        {   // lane ks handles batch row b0+ks (static select, no scratch)
            float sr = 0.f, sz = 0.f, sh = 0.f, sx = 0.f;
#pragma unroll
            for (int b = 0; b < 16; ++b)
                if (b == ks) { sr = aR[b]; sz = aZ[b]; sh = aH[b]; sx = aX[b]; }
            const float hp = hlds[ks][hcg];
            const float r = 1.f / (1.f + expf(-(sr + sbr)));
            const float z = 1.f / (1.f + expf(-(sz + sbz)));
            const float n = tanhf(sx + bxn + r * (sh + bhn));
            const float h = (1.f - z) * n + z * hp;
            hnext[(size_t)(b0 + ks) * HID + hcg] = h;
            h1[((size_t)(b0 + ks) * T_SZ + tg) * H2 + dir * HID + hcg] = h;
        }
        group_barrier(cnt, gen);
    }
}

// ---------------- L1 forward, fused x-GEMM (x = h1 rows, Din=512) -----------
// grid 256 = bt(16 tiles of 8 rows) x hct(16). Group = bt = wg>>4: 16 x 16 WGs.
__global__ __launch_bounds__(256, 2) void l1_scan(
    const float* __restrict__ h1,
    const float* __restrict__ wih, const float* __restrict__ bih,
    const float* __restrict__ whh, const float* __restrict__ bhh,
    float* __restrict__ hbuf,   // [2 par][B][HID]
    unsigned* __restrict__ bar)
{
    __shared__ float hlds[8][256];
    __shared__ float xlds[8][512];
    const int tid = threadIdx.x;
    const int wg  = blockIdx.x;
    const int b0  = (wg >> 4) * 8;
    const int hct = wg & 15;
    const int hc = tid >> 4, ks = tid & 15, ks4 = ks * 4;
    const int hcg = hct * 16 + hc;
    unsigned* cnt = bar + (wg >> 4) * 64;
    unsigned* gen = cnt + 16;

    float Wr[3][16], Wx[3][32];
#pragma unroll
    for (int g = 0; g < 3; ++g) {
#pragma unroll
        for (int j = 0; j < 4; ++j) {
            float4 wv = *(const float4*)(whh + (size_t)(g * HID + hcg) * HID + j * 64 + ks4);
            Wr[g][4 * j] = wv.x; Wr[g][4 * j + 1] = wv.y; Wr[g][4 * j + 2] = wv.z; Wr[g][4 * j + 3] = wv.w;
        }
#pragma unroll
        for (int j = 0; j < 8; ++j) {
            float4 wv = *(const float4*)(wih + (size_t)(g * HID + hcg) * H2 + j * 64 + ks4);
            Wx[g][4 * j] = wv.x; Wx[g][4 * j + 1] = wv.y; Wx[g][4 * j + 2] = wv.z; Wx[g][4 * j + 3] = wv.w;
        }
    }
    const float sbr = bih[hcg] + bhh[hcg];
    const float sbz = bih[HID + hcg] + bhh[HID + hcg];
    const float bxn = bih[2 * HID + hcg];
    const float bhn = bhh[2 * HID + hcg];

    const int r8 = tid >> 5, c32 = (tid & 31) * 4;

    for (int t = 0; t < T_SZ; ++t) {
        const float* hprev = hbuf + (size_t)(t & 1) * B_SZ * HID;
        float* hnext       = hbuf + (size_t)((t + 1) & 1) * B_SZ * HID;

        const float* xsrc = h1 + ((size_t)(b0 + r8) * T_SZ + t) * H2;
#pragma unroll
        for (int p = 0; p < 4; ++p)
            *(float4*)&xlds[r8][p * 128 + c32] = *(const float4*)(xsrc + p * 128 + c32);
        const float* hsrc = hprev + (size_t)(b0 + r8) * HID;
        *(float4*)&hlds[r8][c32]       = *(const float4*)(hsrc + c32);
        *(float4*)&hlds[r8][128 + c32] = *(const float4*)(hsrc + 128 + c32);
        __syncthreads();

        float aR[8], aZ[8], aH[8], aX[8];
#pragma unroll
        for (int b = 0; b < 8; ++b) { aR[b] = 0.f; aZ[b] = 0.f; aH[b] = 0.f; aX[b] = 0.f; }
#pragma unroll
        for (int b = 0; b < 8; ++b) {
#pragma unroll
            for (int j = 0; j < 4; ++j) {
                float4 hv = *(const float4*)&hlds[b][j * 64 + ks4];
                ACC4(aR[b], &Wr[0][4 * j], hv);
                ACC4(aZ[b], &Wr[1][4 * j], hv);
                ACC4(aH[b], &Wr[2][4 * j], hv);
            }
#pragma unroll
            for (int j = 0; j < 8; ++j) {
                float4 xv = *(const float4*)&xlds[b][j * 64 + ks4];
                ACC4(aR[b], &Wx[0][4 * j], xv);
                ACC4(aZ[b], &Wx[1][4 * j], xv);
                ACC4(aX[b], &Wx[2][4 * j], xv);
            }
        }
#pragma unroll
        for (int m = 1; m <= 8; m <<= 1)
#pragma unroll
            for (int b = 0; b < 8; ++b) {
                aR[b] += __shfl_xor(aR[b], m, 64);
                aZ[b] += __shfl_xor(aZ[b], m, 64);
                aH[b] += __shfl_xor(aH[b], m, 64);
                aX[b] += __shfl_xor(aX[b], m, 64);
            }

        if (ks < 8) {
            float sr = 0.f, sz = 0.f, sh = 0.f, sx = 0.f;
#pragma unroll
            for (int b = 0; b < 8; ++b)
                if (b == ks) { sr = aR[b]; sz = aZ[b]; sh = aH[b]; sx = aX[b]; }
            const float hp = hlds[ks][hcg];
            const float r = 1.f / (1.f + expf(-(sr + sbr)));
            const float z = 1.f / (1.f + expf(-(sz + sbz)));
            const float n = tanhf(sx + bxn + r * (sh + bhn));
            const float h = (1.f - z) * n + z * hp;
            hnext[(size_t)(b0 + ks) * HID + hcg] = h;
        }
        group_barrier(cnt, gen);
    }
}

// ---------------- L1 backward: only t=T-1 consumed -> one step from h0=0 ----
__global__ __launch_bounds__(256) void l1r_laststep(
    const float* __restrict__ h1,   // [B][T][512]
    const float* __restrict__ wih,  // [768][512]
    const float* __restrict__ bih, const float* __restrict__ bhh,
    float* __restrict__ h2b)        // [B][256]
{
    const int tid = threadIdx.x;
    const int b  = (blockIdx.x >> 4) * 16 + (tid >> 4);
    const int hc = (blockIdx.x & 15) * 16 + (tid & 15);
    const float* hrow = h1 + ((size_t)b * T_SZ + (T_SZ - 1)) * H2;
    float ar = 0.f, az = 0.f, an = 0.f;
#pragma unroll 8
    for (int k = 0; k < H2; k += 4) {
        float4 hv = *(const float4*)(hrow + k);
        float4 wr = *(const float4*)(wih + (size_t)hc * H2 + k);
        float4 wz = *(const float4*)(wih + (size_t)(HID + hc) * H2 + k);
        float4 wn = *(const float4*)(wih + (size_t)(2 * HID + hc) * H2 + k);
        ar = fmaf(hv.x, wr.x, fmaf(hv.y, wr.y, fmaf(hv.z, wr.z, fmaf(hv.w, wr.w, ar))));
        az = fmaf(hv.x, wz.x, fmaf(hv.y, wz.y, fmaf(hv.z, wz.z, fmaf(hv.w, wz.w, az))));
        an = fmaf(hv.x, wn.x, fmaf(hv.y, wn.y, fmaf(hv.z, wn.z, fmaf(hv.w, wn.w, an))));
    }
    float r = 1.f / (1.f + expf(-(ar + bih[hc] + bhh[hc])));
    float z = 1.f / (1.f + expf(-(az + bih[HID + hc] + bhh[HID + hc])));
    float n = tanhf(an + bih[2 * HID + hc] + r * bhh[2 * HID + hc]);
    h2b[(size_t)b * HID + hc] = (1.f - z) * n;
}

// ---------------- LayerNorm + head ----------------
__global__ __launch_bounds__(256) void ln_head(
    const float* __restrict__ h2f, const float* __restrict__ h2b,
    const float* __restrict__ g, const float* __restrict__ be,
    const float* __restrict__ hw, const float* __restrict__ hb,
    float* __restrict__ out)
{
    __shared__ float v[H2];
    __shared__ float rbuf[8];
    const int b = blockIdx.x, tid = threadIdx.x;
    float xa = h2f[(size_t)b * HID + tid];
    float xb = h2b[(size_t)b * HID + tid];
    float s = xa + xb;
#pragma unroll
    for (int m = 32; m >= 1; m >>= 1) s += __shfl_xor(s, m, 64);
    if ((tid & 63) == 0) rbuf[tid >> 6] = s;
    __syncthreads();
    float mu = (rbuf[0] + rbuf[1] + rbuf[2] + rbuf[3]) * (1.0f / H2);
    float da = xa - mu, db = xb - mu;
    float q = da * da + db * db;
#pragma unroll
    for (int m = 32; m >= 1; m >>= 1) q += __shfl_xor(q, m, 64);
    __syncthreads();
    if ((tid & 63) == 0) rbuf[tid >> 6] = q;
    __syncthreads();
    float var = (rbuf[0] + rbuf[1] + rbuf[2] + rbuf[3]) * (1.0f / H2);
    float rs = rsqrtf(var + 1e-5f);
    v[tid]       = da * rs * g[tid] + be[tid];
    v[HID + tid] = db * rs * g[HID + tid] + be[HID + tid];
    __syncthreads();
    if (tid < NCLS) {
        float a = hb[tid];
        const float* wr = hw + (size_t)tid * H2;
#pragma unroll 4
        for (int k = 0; k < H2; k += 4) {
            float4 wv = *(const float4*)(wr + k);
            a = fmaf(v[k], wv.x, fmaf(v[k + 1], wv.y, fmaf(v[k + 2], wv.z, fmaf(v[k + 3], wv.w, a))));
        }
        out[(size_t)b * NCLS + tid] = a;
    }
}

// ---------------- host ----------------
extern "C" void kernel_launch(void* const* d_in, const int* in_sizes, int n_in,
                              void* d_out, int out_size, void* d_ws, size_t ws_size,
                              hipStream_t stream)
{
    const float* x     = (const float*)d_in[0];
    const float* wih0f = (const float*)d_in[1];
    const float* whh0f = (const float*)d_in[2];
    const float* bih0f = (const float*)d_in[3];
    const float* bhh0f = (const float*)d_in[4];
    const float* wih0b = (const float*)d_in[5];
    const float* whh0b = (const float*)d_in[6];
    const float* bih0b = (const float*)d_in[7];
    const float* bhh0b = (const float*)d_in[8];
    const float* wih1f = (const float*)d_in[9];
    const float* whh1f = (const float*)d_in[10];
    const float* bih1f = (const float*)d_in[11];
    const float* bhh1f = (const float*)d_in[12];
    const float* wih1b = (const float*)d_in[13];
    const float* whh1b = (const float*)d_in[14];
    const float* bih1b = (const float*)d_in[15];
    const float* bhh1b = (const float*)d_in[16];
    const float* lng   = (const float*)d_in[17];
    const float* lnb   = (const float*)d_in[18];
    const float* hw    = (const float*)d_in[19];
    const float* hbb   = (const float*)d_in[20];

    char* wsb = (char*)d_ws;
    size_t off = 0;
    auto alloc = [&](size_t bytes) -> void* {
        void* p = (void*)(wsb + off);
        off += (bytes + 255) & ~(size_t)255;
        return p;
    };
    unsigned* bar = (unsigned*)alloc(32 * 64 * sizeof(unsigned));        // 8 KB
    float* hbufA  = (float*)alloc((size_t)2 * 2 * B_SZ * HID * 4);       // 512 KB
    float* hbufB  = (float*)alloc((size_t)2 * B_SZ * HID * 4);           // 256 KB
    size_t zspan = off;                                                  // bar + h-state
    float* h2b = (float*)alloc((size_t)B_SZ * HID * 4);                  // 128 KB
    float* h1  = (float*)alloc((size_t)B_SZ * T_SZ * H2 * 4);            // 64 MB

    hipMemsetAsync(d_ws, 0, zspan, stream);  // bar + h0 state (re-run per replay)

    l0_scan<<<dim3(256), dim3(256), 0, stream>>>(
        x, wih0f, bih0f, whh0f, bhh0f, wih0b, bih0b, whh0b, bhh0b, hbufA, h1, bar);

    hipMemsetAsync(bar, 0, 32 * 64 * sizeof(unsigned), stream);  // reset gens for L1
    l1r_laststep<<<dim3(128), dim3(256), 0, stream>>>(h1, wih1b, bih1b, bhh1b, h2b);

    l1_scan<<<dim3(256), dim3(256), 0, stream>>>(
        h1, wih1f, bih1f, whh1f, bhh1f, hbufB, bar);

    // L1-fwd final h lands in parity 0 (t=255 writes (255+1)&1 == 0)
    ln_head<<<dim3(B_SZ), dim3(256), 0, stream>>>(hbufB, h2b, lng, lnb, hw, hbb, (float*)d_out);
}

// Round 4
// 6941.389 us; speedup vs baseline: 1.5789x; 1.5789x over previous
//
#include <hip/hip_runtime.h>
#include <math.h>

#define B_SZ 128
#define T_SZ 256
#define DIN  128
#define HID  256
#define H2   512
#define NCLS 250

// ---- coherent (cross-XCD) h exchange: per-access sc0/sc1, no cache-wide fences
__device__ __forceinline__ void h_store(float* p, float v) {
    __hip_atomic_store((unsigned*)p, __float_as_uint(v),
                       __ATOMIC_RELAXED, __HIP_MEMORY_SCOPE_AGENT);
}
__device__ __forceinline__ float h_load(const float* p) {
    return __uint_as_float(__hip_atomic_load((unsigned*)p,
                       __ATOMIC_RELAXED, __HIP_MEMORY_SCOPE_AGENT));
}

// ---- per-group barrier: monotonic relaxed counters, no resets, no fences.
// Correctness chain: sc-flagged h stores -> vmcnt(0) drain inside __syncthreads
// (stores acked at IF$) -> arrival RMW at IF$ -> spinners observe gen -> their
// sc-flagged h loads read IF$. No L2 writeback/invalidate anywhere.
__device__ __forceinline__ void group_barrier(unsigned* cnt, unsigned* gen, int t) {
    __syncthreads();  // includes s_waitcnt vmcnt(0): h stores complete
    if (threadIdx.x == 0) {
        unsigned prev = __hip_atomic_fetch_add(cnt, 1u, __ATOMIC_RELAXED, __HIP_MEMORY_SCOPE_AGENT);
        if (prev == (unsigned)(t * 16 + 15)) {
            __hip_atomic_fetch_add(gen, 1u, __ATOMIC_RELAXED, __HIP_MEMORY_SCOPE_AGENT);
        } else {
            while (__hip_atomic_load(gen, __ATOMIC_RELAXED, __HIP_MEMORY_SCOPE_AGENT)
                   < (unsigned)(t + 1))
                __builtin_amdgcn_s_sleep(1);
        }
    }
    __syncthreads();
}

#define ACC4(A, Wp, v) \
    A = fmaf((v).x, (Wp)[0], A); A = fmaf((v).y, (Wp)[1], A); \
    A = fmaf((v).z, (Wp)[2], A); A = fmaf((v).w, (Wp)[3], A)

// ---------------- L0: both dirs, fused x-GEMM, persistent scan --------------
// grid 256 = dir(2) x bt(8 tiles of 16 rows) x hct(16 tiles of 16 cols).
// Group = (dir,bt) = wg>>4: 16 groups x 16 WGs. Thread (hc,ks): 16-way k-split.
__global__ __launch_bounds__(256, 2) void l0_scan(
    const float* __restrict__ x,
    const float* __restrict__ wihf, const float* __restrict__ bihf,
    const float* __restrict__ whhf, const float* __restrict__ bhhf,
    const float* __restrict__ wihb, const float* __restrict__ bihb,
    const float* __restrict__ whhb, const float* __restrict__ bhhb,
    float* __restrict__ hbuf,   // [2 dir][2 par][B][HID]
    float* __restrict__ h1,     // [B][T][512]
    unsigned* __restrict__ bar)
{
    __shared__ float hlds[16][256];
    __shared__ float xlds[16][128];
    const int tid = threadIdx.x;
    const int wg  = blockIdx.x;
    const int dir = wg >> 7;
    const int rem = wg & 127;
    const int b0  = (rem >> 4) * 16;
    const int hct = rem & 15;
    const int hc = tid >> 4, ks = tid & 15, ks4 = ks * 4;
    const int hcg = hct * 16 + hc;
    unsigned* cnt = bar + (wg >> 4) * 64;
    unsigned* gen = cnt + 16;

    const float* wih = dir ? wihb : wihf;
    const float* bih = dir ? bihb : bihf;
    const float* whh = dir ? whhb : whhf;
    const float* bhh = dir ? bhhb : bhhf;

    float Wr[3][16], Wx[3][8];
#pragma unroll
    for (int g = 0; g < 3; ++g) {
#pragma unroll
        for (int j = 0; j < 4; ++j) {
            float4 wv = *(const float4*)(whh + (size_t)(g * HID + hcg) * HID + j * 64 + ks4);
            Wr[g][4 * j] = wv.x; Wr[g][4 * j + 1] = wv.y; Wr[g][4 * j + 2] = wv.z; Wr[g][4 * j + 3] = wv.w;
        }
#pragma unroll
        for (int j = 0; j < 2; ++j) {
            float4 wv = *(const float4*)(wih + (size_t)(g * HID + hcg) * DIN + j * 64 + ks4);
            Wx[g][4 * j] = wv.x; Wx[g][4 * j + 1] = wv.y; Wx[g][4 * j + 2] = wv.z; Wx[g][4 * j + 3] = wv.w;
        }
    }
    const float sbr = bih[hcg] + bhh[hcg];
    const float sbz = bih[HID + hcg] + bhh[HID + hcg];
    const float bxn = bih[2 * HID + hcg];
    const float bhn = bhh[2 * HID + hcg];

    float* hb = hbuf + (size_t)dir * 2 * B_SZ * HID;
    const int r8 = tid >> 5, c32 = (tid & 31) * 4;

    for (int t = 0; t < T_SZ; ++t) {
        const int tg = dir ? (T_SZ - 1 - t) : t;
        const float* hprev = hb + (size_t)(t & 1) * B_SZ * HID;
        float* hnext       = hb + (size_t)((t + 1) & 1) * B_SZ * HID;

        // x tile: normal cached loads (read-only input, L2 stays warm now)
#pragma unroll
        for (int p = 0; p < 2; ++p) {
            const int row = p * 8 + r8;
            *(float4*)&xlds[row][c32] =
                *(const float4*)(x + ((size_t)(b0 + row) * T_SZ + tg) * DIN + c32);
        }
        // h tile: coherent scalar loads from IF$ (16 per thread, pipelined)
#pragma unroll
        for (int i = 0; i < 16; ++i)
            hlds[i][tid] = h_load(hprev + (size_t)(b0 + i) * HID + tid);
        __syncthreads();

        float aR[16], aZ[16], aH[16], aX[16];
#pragma unroll
        for (int b = 0; b < 16; ++b) { aR[b] = 0.f; aZ[b] = 0.f; aH[b] = 0.f; aX[b] = 0.f; }
#pragma unroll
        for (int b = 0; b < 16; ++b) {
#pragma unroll
            for (int j = 0; j < 4; ++j) {
                float4 hv = *(const float4*)&hlds[b][j * 64 + ks4];
                ACC4(aR[b], &Wr[0][4 * j], hv);
                ACC4(aZ[b], &Wr[1][4 * j], hv);
                ACC4(aH[b], &Wr[2][4 * j], hv);
            }
#pragma unroll
            for (int j = 0; j < 2; ++j) {
                float4 xv = *(const float4*)&xlds[b][j * 64 + ks4];
                ACC4(aR[b], &Wx[0][4 * j], xv);
                ACC4(aZ[b], &Wx[1][4 * j], xv);
                ACC4(aX[b], &Wx[2][4 * j], xv);
            }
        }
#pragma unroll
        for (int m = 1; m <= 8; m <<= 1)
#pragma unroll
            for (int b = 0; b < 16; ++b) {
                aR[b] += __shfl_xor(aR[b], m, 64);
                aZ[b] += __shfl_xor(aZ[b], m, 64);
                aH[b] += __shfl_xor(aH[b], m, 64);
                aX[b] += __shfl_xor(aX[b], m, 64);
            }

        {   // lane ks handles batch row b0+ks (static select, no scratch)
            float sr = 0.f, sz = 0.f, sh = 0.f, sx = 0.f;
#pragma unroll
            for (int b = 0; b < 16; ++b)
                if (b == ks) { sr = aR[b]; sz = aZ[b]; sh = aH[b]; sx = aX[b]; }
            const float hp = hlds[ks][hcg];
            const float r = 1.f / (1.f + expf(-(sr + sbr)));
            const float z = 1.f / (1.f + expf(-(sz + sbz)));
            const float n = tanhf(sx + bxn + r * (sh + bhn));
            const float h = (1.f - z) * n + z * hp;
            h_store(hnext + (size_t)(b0 + ks) * HID + hcg, h);           // coherent
            h1[((size_t)(b0 + ks) * T_SZ + tg) * H2 + dir * HID + hcg] = h;  // normal (next kernel)
        }
        group_barrier(cnt, gen, t);
    }
}

// ---------------- L1 forward, fused x-GEMM (x = h1 rows, Din=512) -----------
// grid 256 = bt(16 tiles of 8 rows) x hct(16). Group = bt = wg>>4: 16 x 16 WGs.
__global__ __launch_bounds__(256, 2) void l1_scan(
    const float* __restrict__ h1,
    const float* __restrict__ wih, const float* __restrict__ bih,
    const float* __restrict__ whh, const float* __restrict__ bhh,
    float* __restrict__ hbuf,   // [2 par][B][HID]
    unsigned* __restrict__ bar)
{
    __shared__ float hlds[8][256];
    __shared__ float xlds[8][512];
    const int tid = threadIdx.x;
    const int wg  = blockIdx.x;
    const int b0  = (wg >> 4) * 8;
    const int hct = wg & 15;
    const int hc = tid >> 4, ks = tid & 15, ks4 = ks * 4;
    const int hcg = hct * 16 + hc;
    unsigned* cnt = bar + (wg >> 4) * 64;
    unsigned* gen = cnt + 16;

    float Wr[3][16], Wx[3][32];
#pragma unroll
    for (int g = 0; g < 3; ++g) {
#pragma unroll
        for (int j = 0; j < 4; ++j) {
            float4 wv = *(const float4*)(whh + (size_t)(g * HID + hcg) * HID + j * 64 + ks4);
            Wr[g][4 * j] = wv.x; Wr[g][4 * j + 1] = wv.y; Wr[g][4 * j + 2] = wv.z; Wr[g][4 * j + 3] = wv.w;
        }
#pragma unroll
        for (int j = 0; j < 8; ++j) {
            float4 wv = *(const float4*)(wih + (size_t)(g * HID + hcg) * H2 + j * 64 + ks4);
            Wx[g][4 * j] = wv.x; Wx[g][4 * j + 1] = wv.y; Wx[g][4 * j + 2] = wv.z; Wx[g][4 * j + 3] = wv.w;
        }
    }
    const float sbr = bih[hcg] + bhh[hcg];
    const float sbz = bih[HID + hcg] + bhh[HID + hcg];
    const float bxn = bih[2 * HID + hcg];
    const float bhn = bhh[2 * HID + hcg];

    const int r8 = tid >> 5, c32 = (tid & 31) * 4;

    for (int t = 0; t < T_SZ; ++t) {
        const float* hprev = hbuf + (size_t)(t & 1) * B_SZ * HID;
        float* hnext       = hbuf + (size_t)((t + 1) & 1) * B_SZ * HID;

        const float* xsrc = h1 + ((size_t)(b0 + r8) * T_SZ + t) * H2;  // normal cached
#pragma unroll
        for (int p = 0; p < 4; ++p)
            *(float4*)&xlds[r8][p * 128 + c32] = *(const float4*)(xsrc + p * 128 + c32);
#pragma unroll
        for (int i = 0; i < 8; ++i)
            hlds[i][tid] = h_load(hprev + (size_t)(b0 + i) * HID + tid);
        __syncthreads();

        float aR[8], aZ[8], aH[8], aX[8];
#pragma unroll
        for (int b = 0; b < 8; ++b) { aR[b] = 0.f; aZ[b] = 0.f; aH[b] = 0.f; aX[b] = 0.f; }
#pragma unroll
        for (int b = 0; b < 8; ++b) {
#pragma unroll
            for (int j = 0; j < 4; ++j) {
                float4 hv = *(const float4*)&hlds[b][j * 64 + ks4];
                ACC4(aR[b], &Wr[0][4 * j], hv);
                ACC4(aZ[b], &Wr[1][4 * j], hv);
                ACC4(aH[b], &Wr[2][4 * j], hv);
            }
#pragma unroll
            for (int j = 0; j < 8; ++j) {
                float4 xv = *(const float4*)&xlds[b][j * 64 + ks4];
                ACC4(aR[b], &Wx[0][4 * j], xv);
                ACC4(aZ[b], &Wx[1][4 * j], xv);
                ACC4(aX[b], &Wx[2][4 * j], xv);
            }
        }
#pragma unroll
        for (int m = 1; m <= 8; m <<= 1)
#pragma unroll
            for (int b = 0; b < 8; ++b) {
                aR[b] += __shfl_xor(aR[b], m, 64);
                aZ[b] += __shfl_xor(aZ[b], m, 64);
                aH[b] += __shfl_xor(aH[b], m, 64);
                aX[b] += __shfl_xor(aX[b], m, 64);
            }

        if (ks < 8) {
            float sr = 0.f, sz = 0.f, sh = 0.f, sx = 0.f;
#pragma unroll
            for (int b = 0; b < 8; ++b)
                if (b == ks) { sr = aR[b]; sz = aZ[b]; sh = aH[b]; sx = aX[b]; }
            const float hp = hlds[ks][hcg];
            const float r = 1.f / (1.f + expf(-(sr + sbr)));
            const float z = 1.f / (1.f + expf(-(sz + sbz)));
            const float n = tanhf(sx + bxn + r * (sh + bhn));
            const float h = (1.f - z) * n + z * hp;
            h_store(hnext + (size_t)(b0 + ks) * HID + hcg, h);
        }
        group_barrier(cnt, gen, t);
    }
}

// ---------------- L1 backward: only t=T-1 consumed -> one step from h0=0 ----
__global__ __launch_bounds__(256) void l1r_laststep(
    const float* __restrict__ h1,   // [B][T][512]
    const float* __restrict__ wih,  // [768][512]
    const float* __restrict__ bih, const float* __restrict__ bhh,
    float* __restrict__ h2b)        // [B][256]
{
    const int tid = threadIdx.x;
    const int b  = (blockIdx.x >> 4) * 16 + (tid >> 4);
    const int hc = (blockIdx.x & 15) * 16 + (tid & 15);
    const float* hrow = h1 + ((size_t)b * T_SZ + (T_SZ - 1)) * H2;
    float ar = 0.f, az = 0.f, an = 0.f;
#pragma unroll 8
    for (int k = 0; k < H2; k += 4) {
        float4 hv = *(const float4*)(hrow + k);
        float4 wr = *(const float4*)(wih + (size_t)hc * H2 + k);
        float4 wz = *(const float4*)(wih + (size_t)(HID + hc) * H2 + k);
        float4 wn = *(const float4*)(wih + (size_t)(2 * HID + hc) * H2 + k);
        ar = fmaf(hv.x, wr.x, fmaf(hv.y, wr.y, fmaf(hv.z, wr.z, fmaf(hv.w, wr.w, ar))));
        az = fmaf(hv.x, wz.x, fmaf(hv.y, wz.y, fmaf(hv.z, wz.z, fmaf(hv.w, wz.w, az))));
        an = fmaf(hv.x, wn.x, fmaf(hv.y, wn.y, fmaf(hv.z, wn.z, fmaf(hv.w, wn.w, an))));
    }
    float r = 1.f / (1.f + expf(-(ar + bih[hc] + bhh[hc])));
    float z = 1.f / (1.f + expf(-(az + bih[HID + hc] + bhh[HID + hc])));
    float n = tanhf(an + bih[2 * HID + hc] + r * bhh[2 * HID + hc]);
    h2b[(size_t)b * HID + hc] = (1.f - z) * n;
}

// ---------------- LayerNorm + head ----------------
__global__ __launch_bounds__(256) void ln_head(
    const float* __restrict__ h2f, const float* __restrict__ h2b,
    const float* __restrict__ g, const float* __restrict__ be,
    const float* __restrict__ hw, const float* __restrict__ hb,
    float* __restrict__ out)
{
    __shared__ float v[H2];
    __shared__ float rbuf[8];
    const int b = blockIdx.x, tid = threadIdx.x;
    float xa = h2f[(size_t)b * HID + tid];
    float xb = h2b[(size_t)b * HID + tid];
    float s = xa + xb;
#pragma unroll
    for (int m = 32; m >= 1; m >>= 1) s += __shfl_xor(s, m, 64);
    if ((tid & 63) == 0) rbuf[tid >> 6] = s;
    __syncthreads();
    float mu = (rbuf[0] + rbuf[1] + rbuf[2] + rbuf[3]) * (1.0f / H2);
    float da = xa - mu, db = xb - mu;
    float q = da * da + db * db;
#pragma unroll
    for (int m = 32; m >= 1; m >>= 1) q += __shfl_xor(q, m, 64);
    __syncthreads();
    if ((tid & 63) == 0) rbuf[tid >> 6] = q;
    __syncthreads();
    float var = (rbuf[0] + rbuf[1] + rbuf[2] + rbuf[3]) * (1.0f / H2);
    float rs = rsqrtf(var + 1e-5f);
    v[tid]       = da * rs * g[tid] + be[tid];
    v[HID + tid] = db * rs * g[HID + tid] + be[HID + tid];
    __syncthreads();
    if (tid < NCLS) {
        float a = hb[tid];
        const float* wr = hw + (size_t)tid * H2;
#pragma unroll 4
        for (int k = 0; k < H2; k += 4) {
            float4 wv = *(const float4*)(wr + k);
            a = fmaf(v[k], wv.x, fmaf(v[k + 1], wv.y, fmaf(v[k + 2], wv.z, fmaf(v[k + 3], wv.w, a))));
        }
        out[(size_t)b * NCLS + tid] = a;
    }
}

// ---------------- host ----------------
extern "C" void kernel_launch(void* const* d_in, const int* in_sizes, int n_in,
                              void* d_out, int out_size, void* d_ws, size_t ws_size,
                              hipStream_t stream)
{
    const float* x     = (const float*)d_in[0];
    const float* wih0f = (const float*)d_in[1];
    const float* whh0f = (const float*)d_in[2];
    const float* bih0f = (const float*)d_in[3];
    const float* bhh0f = (const float*)d_in[4];
    const float* wih0b = (const float*)d_in[5];
    const float* whh0b = (const float*)d_in[6];
    const float* bih0b = (const float*)d_in[7];
    const float* bhh0b = (const float*)d_in[8];
    const float* wih1f = (const float*)d_in[9];
    const float* whh1f = (const float*)d_in[10];
    const float* bih1f = (const float*)d_in[11];
    const float* bhh1f = (const float*)d_in[12];
    const float* wih1b = (const float*)d_in[13];
    const float* whh1b = (const float*)d_in[14];
    const float* bih1b = (const float*)d_in[15];
    const float* bhh1b = (const float*)d_in[16];
    const float* lng   = (const float*)d_in[17];
    const float* lnb   = (const float*)d_in[18];
    const float* hw    = (const float*)d_in[19];
    const float* hbb   = (const float*)d_in[20];

    char* wsb = (char*)d_ws;
    size_t off = 0;
    auto alloc = [&](size_t bytes) -> void* {
        void* p = (void*)(wsb + off);
        off += (bytes + 255) & ~(size_t)255;
        return p;
    };
    unsigned* bar = (unsigned*)alloc(32 * 64 * sizeof(unsigned));        // 8 KB
    float* hbufA  = (float*)alloc((size_t)2 * 2 * B_SZ * HID * 4);       // 512 KB
    float* hbufB  = (float*)alloc((size_t)2 * B_SZ * HID * 4);           // 256 KB
    size_t zspan = off;                                                  // bar + h-state
    float* h2b = (float*)alloc((size_t)B_SZ * HID * 4);                  // 128 KB
    float* h1  = (float*)alloc((size_t)B_SZ * T_SZ * H2 * 4);            // 64 MB

    hipMemsetAsync(d_ws, 0, zspan, stream);  // bar + h0 state (re-run per replay)

    l0_scan<<<dim3(256), dim3(256), 0, stream>>>(
        x, wih0f, bih0f, whh0f, bhh0f, wih0b, bih0b, whh0b, bhh0b, hbufA, h1, bar);

    hipMemsetAsync(bar, 0, 32 * 64 * sizeof(unsigned), stream);  // reset counters for L1
    l1r_laststep<<<dim3(128), dim3(256), 0, stream>>>(h1, wih1b, bih1b, bhh1b, h2b);

    l1_scan<<<dim3(256), dim3(256), 0, stream>>>(
        h1, wih1f, bih1f, whh1f, bhh1f, hbufB, bar);

    // L1-fwd final h lands in parity 0 (t=255 writes (255+1)&1 == 0)
    ln_head<<<dim3(B_SZ), dim3(256), 0, stream>>>(hbufB, h2b, lng, lnb, hw, hbb, (float*)d_out);
}

// Round 5
// 5036.037 us; speedup vs baseline: 2.1763x; 1.3783x over previous
//
#include <hip/hip_runtime.h>
#include <math.h>

#define B_SZ 128
#define T_SZ 256
#define DIN  128
#define HID  256
#define H2   512
#define NCLS 250

// ---- coherent (cross-XCD) h exchange: per-access sc0/sc1, no cache-wide fences
__device__ __forceinline__ void h_store(float* p, float v) {
    __hip_atomic_store((unsigned*)p, __float_as_uint(v),
                       __ATOMIC_RELAXED, __HIP_MEMORY_SCOPE_AGENT);
}
__device__ __forceinline__ float h_load(const float* p) {
    return __uint_as_float(__hip_atomic_load((unsigned*)p,
                       __ATOMIC_RELAXED, __HIP_MEMORY_SCOPE_AGENT));
}

// ---- per-group barrier: monotonic relaxed counters, no resets, no fences.
__device__ __forceinline__ void group_barrier(unsigned* cnt, unsigned* gen, int t) {
    __syncthreads();  // includes s_waitcnt vmcnt(0): h stores complete
    if (threadIdx.x == 0) {
        unsigned prev = __hip_atomic_fetch_add(cnt, 1u, __ATOMIC_RELAXED, __HIP_MEMORY_SCOPE_AGENT);
        if (prev == (unsigned)(t * 16 + 15)) {
            __hip_atomic_fetch_add(gen, 1u, __ATOMIC_RELAXED, __HIP_MEMORY_SCOPE_AGENT);
        } else {
            while (__hip_atomic_load(gen, __ATOMIC_RELAXED, __HIP_MEMORY_SCOPE_AGENT)
                   < (unsigned)(t + 1)) {}
        }
    }
    __syncthreads();
}

#define ACC4(A, Wp, v) \
    A = fmaf((v).x, (Wp)[0], A); A = fmaf((v).y, (Wp)[1], A); \
    A = fmaf((v).z, (Wp)[2], A); A = fmaf((v).w, (Wp)[3], A)

// ---------------- L0: both dirs, fused x-GEMM, persistent scan --------------
// grid 256 = dir(2) x bt(8 tiles of 16 rows) x hct(16 tiles of 16 cols).
// Group = (dir,bt) = wg>>4: 16 groups x 16 WGs. Thread (hc,ks): 16-way k-split.
__global__ __launch_bounds__(256, 2) void l0_scan(
    const float* __restrict__ x,
    const float* __restrict__ wihf, const float* __restrict__ bihf,
    const float* __restrict__ whhf, const float* __restrict__ bhhf,
    const float* __restrict__ wihb, const float* __restrict__ bihb,
    const float* __restrict__ whhb, const float* __restrict__ bhhb,
    float* __restrict__ hbuf,   // [2 dir][2 par][B][HID]
    float* __restrict__ h1,     // [B][T][512]
    unsigned* __restrict__ bar)
{
    __shared__ float hlds[16][256];
    __shared__ float xlds[16][128];
    __shared__ float hst[16][17];   // padded: <=2-way bank alias
    const int tid = threadIdx.x;
    const int wg  = blockIdx.x;
    const int dir = wg >> 7;
    const int rem = wg & 127;
    const int b0  = (rem >> 4) * 16;
    const int hct = rem & 15;
    const int hc = tid >> 4, ks = tid & 15, ks4 = ks * 4;
    const int hcg = hct * 16 + hc;
    unsigned* cnt = bar + (wg >> 4) * 64;
    unsigned* gen = cnt + 16;

    const float* wih = dir ? wihb : wihf;
    const float* bih = dir ? bihb : bihf;
    const float* whh = dir ? whhb : whhf;
    const float* bhh = dir ? bhhb : bhhf;

    float Wr[3][16], Wx[3][8];
#pragma unroll
    for (int g = 0; g < 3; ++g) {
#pragma unroll
        for (int j = 0; j < 4; ++j) {
            float4 wv = *(const float4*)(whh + (size_t)(g * HID + hcg) * HID + j * 64 + ks4);
            Wr[g][4 * j] = wv.x; Wr[g][4 * j + 1] = wv.y; Wr[g][4 * j + 2] = wv.z; Wr[g][4 * j + 3] = wv.w;
        }
#pragma unroll
        for (int j = 0; j < 2; ++j) {
            float4 wv = *(const float4*)(wih + (size_t)(g * HID + hcg) * DIN + j * 64 + ks4);
            Wx[g][4 * j] = wv.x; Wx[g][4 * j + 1] = wv.y; Wx[g][4 * j + 2] = wv.z; Wx[g][4 * j + 3] = wv.w;
        }
    }
    const float sbr = bih[hcg] + bhh[hcg];
    const float sbz = bih[HID + hcg] + bhh[HID + hcg];
    const float bxn = bih[2 * HID + hcg];
    const float bhn = bhh[2 * HID + hcg];

    float* hb = hbuf + (size_t)dir * 2 * B_SZ * HID;
    const int r8 = tid >> 5, c32 = (tid & 31) * 4;

    // prefetch x tile for t=0
    float4 xp[2];
    {
        const int tg0 = dir ? (T_SZ - 1) : 0;
#pragma unroll
        for (int p = 0; p < 2; ++p)
            xp[p] = *(const float4*)(x + ((size_t)(b0 + p * 8 + r8) * T_SZ + tg0) * DIN + c32);
    }

    for (int t = 0; t < T_SZ; ++t) {
        const int tg = dir ? (T_SZ - 1 - t) : t;
        const float* hprev = hb + (size_t)(t & 1) * B_SZ * HID;
        float* hnext       = hb + (size_t)((t + 1) & 1) * B_SZ * HID;

        // coherent h loads first (critical path); cluster loads, then LDS writes
        float hv[16];
#pragma unroll
        for (int i = 0; i < 16; ++i)
            hv[i] = h_load(hprev + (size_t)(b0 + i) * HID + tid);
#pragma unroll
        for (int p = 0; p < 2; ++p)
            *(float4*)&xlds[p * 8 + r8][c32] = xp[p];
#pragma unroll
        for (int i = 0; i < 16; ++i)
            hlds[i][tid] = hv[i];
        __syncthreads();

        // prefetch next step's x tile (hidden under compute + barrier)
        {
            const int tn  = (t + 1 < T_SZ) ? (t + 1) : t;
            const int tgn = dir ? (T_SZ - 1 - tn) : tn;
#pragma unroll
            for (int p = 0; p < 2; ++p)
                xp[p] = *(const float4*)(x + ((size_t)(b0 + p * 8 + r8) * T_SZ + tgn) * DIN + c32);
        }

        float aR[16], aZ[16], aH[16], aX[16];
#pragma unroll
        for (int b = 0; b < 16; ++b) { aR[b] = 0.f; aZ[b] = 0.f; aH[b] = 0.f; aX[b] = 0.f; }
#pragma unroll
        for (int b = 0; b < 16; ++b) {
#pragma unroll
            for (int j = 0; j < 4; ++j) {
                float4 hv4 = *(const float4*)&hlds[b][j * 64 + ks4];
                ACC4(aR[b], &Wr[0][4 * j], hv4);
                ACC4(aZ[b], &Wr[1][4 * j], hv4);
                ACC4(aH[b], &Wr[2][4 * j], hv4);
            }
#pragma unroll
            for (int j = 0; j < 2; ++j) {
                float4 xv = *(const float4*)&xlds[b][j * 64 + ks4];
                ACC4(aR[b], &Wx[0][4 * j], xv);
                ACC4(aZ[b], &Wx[1][4 * j], xv);
                ACC4(aX[b], &Wx[2][4 * j], xv);
            }
        }
#pragma unroll
        for (int m = 1; m <= 8; m <<= 1)
#pragma unroll
            for (int b = 0; b < 16; ++b) {
                aR[b] += __shfl_xor(aR[b], m, 64);
                aZ[b] += __shfl_xor(aZ[b], m, 64);
                aH[b] += __shfl_xor(aH[b], m, 64);
                aX[b] += __shfl_xor(aX[b], m, 64);
            }

        {   // lane ks owns batch row b0+ks; stage to LDS for coalesced store
            float sr = 0.f, sz = 0.f, sh = 0.f, sx = 0.f;
#pragma unroll
            for (int b = 0; b < 16; ++b)
                if (b == ks) { sr = aR[b]; sz = aZ[b]; sh = aH[b]; sx = aX[b]; }
            const float hp = hlds[ks][hcg];
            const float r = 1.f / (1.f + expf(-(sr + sbr)));
            const float z = 1.f / (1.f + expf(-(sz + sbz)));
            const float n = tanhf(sx + bxn + r * (sh + bhn));
            hst[ks][hc] = (1.f - z) * n + z * hp;
        }
        __syncthreads();
        {   // cooperative coalesced store: 16 lanes -> one 64B line
            const int r = tid >> 4, c = tid & 15;
            const float hval = hst[r][c];
            h_store(hnext + (size_t)(b0 + r) * HID + hct * 16 + c, hval);
            h1[((size_t)(b0 + r) * T_SZ + tg) * H2 + dir * HID + hct * 16 + c] = hval;
        }
        group_barrier(cnt, gen, t);
    }
}

// ---------------- L1 forward, fused x-GEMM (x = h1 rows, Din=512) -----------
// grid 256 = bt(16 tiles of 8 rows) x hct(16). Group = bt = wg>>4: 16 x 16 WGs.
__global__ __launch_bounds__(256, 2) void l1_scan(
    const float* __restrict__ h1,
    const float* __restrict__ wih, const float* __restrict__ bih,
    const float* __restrict__ whh, const float* __restrict__ bhh,
    float* __restrict__ hbuf,   // [2 par][B][HID]
    unsigned* __restrict__ bar)
{
    __shared__ float hlds[8][256];
    __shared__ float xlds[8][512];
    __shared__ float hst[8][17];
    const int tid = threadIdx.x;
    const int wg  = blockIdx.x;
    const int b0  = (wg >> 4) * 8;
    const int hct = wg & 15;
    const int hc = tid >> 4, ks = tid & 15, ks4 = ks * 4;
    const int hcg = hct * 16 + hc;
    unsigned* cnt = bar + (wg >> 4) * 64;
    unsigned* gen = cnt + 16;

    float Wr[3][16], Wx[3][32];
#pragma unroll
    for (int g = 0; g < 3; ++g) {
#pragma unroll
        for (int j = 0; j < 4; ++j) {
            float4 wv = *(const float4*)(whh + (size_t)(g * HID + hcg) * HID + j * 64 + ks4);
            Wr[g][4 * j] = wv.x; Wr[g][4 * j + 1] = wv.y; Wr[g][4 * j + 2] = wv.z; Wr[g][4 * j + 3] = wv.w;
        }
#pragma unroll
        for (int j = 0; j < 8; ++j) {
            float4 wv = *(const float4*)(wih + (size_t)(g * HID + hcg) * H2 + j * 64 + ks4);
            Wx[g][4 * j] = wv.x; Wx[g][4 * j + 1] = wv.y; Wx[g][4 * j + 2] = wv.z; Wx[g][4 * j + 3] = wv.w;
        }
    }
    const float sbr = bih[hcg] + bhh[hcg];
    const float sbz = bih[HID + hcg] + bhh[HID + hcg];
    const float bxn = bih[2 * HID + hcg];
    const float bhn = bhh[2 * HID + hcg];

    const int r8 = tid >> 5, c32 = (tid & 31) * 4;

    float4 xp[4];
    {
        const float* xsrc = h1 + ((size_t)(b0 + r8) * T_SZ + 0) * H2;
#pragma unroll
        for (int p = 0; p < 4; ++p)
            xp[p] = *(const float4*)(xsrc + p * 128 + c32);
    }

    for (int t = 0; t < T_SZ; ++t) {
        const float* hprev = hbuf + (size_t)(t & 1) * B_SZ * HID;
        float* hnext       = hbuf + (size_t)((t + 1) & 1) * B_SZ * HID;

        float hv[8];
#pragma unroll
        for (int i = 0; i < 8; ++i)
            hv[i] = h_load(hprev + (size_t)(b0 + i) * HID + tid);
#pragma unroll
        for (int p = 0; p < 4; ++p)
            *(float4*)&xlds[r8][p * 128 + c32] = xp[p];
#pragma unroll
        for (int i = 0; i < 8; ++i)
            hlds[i][tid] = hv[i];
        __syncthreads();

        {   // prefetch next x tile (h1 rows) — hidden under compute + barrier
            const int tn = (t + 1 < T_SZ) ? (t + 1) : t;
            const float* xsrc = h1 + ((size_t)(b0 + r8) * T_SZ + tn) * H2;
#pragma unroll
            for (int p = 0; p < 4; ++p)
                xp[p] = *(const float4*)(xsrc + p * 128 + c32);
        }

        float aR[8], aZ[8], aH[8], aX[8];
#pragma unroll
        for (int b = 0; b < 8; ++b) { aR[b] = 0.f; aZ[b] = 0.f; aH[b] = 0.f; aX[b] = 0.f; }
#pragma unroll
        for (int b = 0; b < 8; ++b) {
#pragma unroll
            for (int j = 0; j < 4; ++j) {
                float4 hv4 = *(const float4*)&hlds[b][j * 64 + ks4];
                ACC4(aR[b], &Wr[0][4 * j], hv4);
                ACC4(aZ[b], &Wr[1][4 * j], hv4);
                ACC4(aH[b], &Wr[2][4 * j], hv4);
            }
#pragma unroll
            for (int j = 0; j < 8; ++j) {
                float4 xv = *(const float4*)&xlds[b][j * 64 + ks4];
                ACC4(aR[b], &Wx[0][4 * j], xv);
                ACC4(aZ[b], &Wx[1][4 * j], xv);
                ACC4(aX[b], &Wx[2][4 * j], xv);
            }
        }
#pragma unroll
        for (int m = 1; m <= 8; m <<= 1)
#pragma unroll
            for (int b = 0; b < 8; ++b) {
                aR[b] += __shfl_xor(aR[b], m, 64);
                aZ[b] += __shfl_xor(aZ[b], m, 64);
                aH[b] += __shfl_xor(aH[b], m, 64);
                aX[b] += __shfl_xor(aX[b], m, 64);
            }

        if (ks < 8) {
            float sr = 0.f, sz = 0.f, sh = 0.f, sx = 0.f;
#pragma unroll
            for (int b = 0; b < 8; ++b)
                if (b == ks) { sr = aR[b]; sz = aZ[b]; sh = aH[b]; sx = aX[b]; }
            const float hp = hlds[ks][hcg];
            const float r = 1.f / (1.f + expf(-(sr + sbr)));
            const float z = 1.f / (1.f + expf(-(sz + sbz)));
            const float n = tanhf(sx + bxn + r * (sh + bhn));
            hst[ks][hc] = (1.f - z) * n + z * hp;
        }
        __syncthreads();
        if (tid < 128) {   // coalesced coherent store: 16 lanes -> one 64B line
            const int r = tid >> 4, c = tid & 15;
            h_store(hnext + (size_t)(b0 + r) * HID + hct * 16 + c, hst[r][c]);
        }
        group_barrier(cnt, gen, t);
    }
}

// ---------------- L1 backward: only t=T-1 consumed -> one step from h0=0 ----
__global__ __launch_bounds__(256) void l1r_laststep(
    const float* __restrict__ h1,   // [B][T][512]
    const float* __restrict__ wih,  // [768][512]
    const float* __restrict__ bih, const float* __restrict__ bhh,
    float* __restrict__ h2b)        // [B][256]
{
    const int tid = threadIdx.x;
    const int b  = (blockIdx.x >> 4) * 16 + (tid >> 4);
    const int hc = (blockIdx.x & 15) * 16 + (tid & 15);
    const float* hrow = h1 + ((size_t)b * T_SZ + (T_SZ - 1)) * H2;
    float ar = 0.f, az = 0.f, an = 0.f;
#pragma unroll 8
    for (int k = 0; k < H2; k += 4) {
        float4 hv = *(const float4*)(hrow + k);
        float4 wr = *(const float4*)(wih + (size_t)hc * H2 + k);
        float4 wz = *(const float4*)(wih + (size_t)(HID + hc) * H2 + k);
        float4 wn = *(const float4*)(wih + (size_t)(2 * HID + hc) * H2 + k);
        ar = fmaf(hv.x, wr.x, fmaf(hv.y, wr.y, fmaf(hv.z, wr.z, fmaf(hv.w, wr.w, ar))));
        az = fmaf(hv.x, wz.x, fmaf(hv.y, wz.y, fmaf(hv.z, wz.z, fmaf(hv.w, wz.w, az))));
        an = fmaf(hv.x, wn.x, fmaf(hv.y, wn.y, fmaf(hv.z, wn.z, fmaf(hv.w, wn.w, an))));
    }
    float r = 1.f / (1.f + expf(-(ar + bih[hc] + bhh[hc])));
    float z = 1.f / (1.f + expf(-(az + bih[HID + hc] + bhh[HID + hc])));
    float n = tanhf(an + bih[2 * HID + hc] + r * bhh[2 * HID + hc]);
    h2b[(size_t)b * HID + hc] = (1.f - z) * n;
}

// ---------------- LayerNorm + head ----------------
__global__ __launch_bounds__(256) void ln_head(
    const float* __restrict__ h2f, const float* __restrict__ h2b,
    const float* __restrict__ g, const float* __restrict__ be,
    const float* __restrict__ hw, const float* __restrict__ hb,
    float* __restrict__ out)
{
    __shared__ float v[H2];
    __shared__ float rbuf[8];
    const int b = blockIdx.x, tid = threadIdx.x;
    float xa = h2f[(size_t)b * HID + tid];
    float xb = h2b[(size_t)b * HID + tid];
    float s = xa + xb;
#pragma unroll
    for (int m = 32; m >= 1; m >>= 1) s += __shfl_xor(s, m, 64);
    if ((tid & 63) == 0) rbuf[tid >> 6] = s;
    __syncthreads();
    float mu = (rbuf[0] + rbuf[1] + rbuf[2] + rbuf[3]) * (1.0f / H2);
    float da = xa - mu, db = xb - mu;
    float q = da * da + db * db;
#pragma unroll
    for (int m = 32; m >= 1; m >>= 1) q += __shfl_xor(q, m, 64);
    __syncthreads();
    if ((tid & 63) == 0) rbuf[tid >> 6] = q;
    __syncthreads();
    float var = (rbuf[0] + rbuf[1] + rbuf[2] + rbuf[3]) * (1.0f / H2);
    float rs = rsqrtf(var + 1e-5f);
    v[tid]       = da * rs * g[tid] + be[tid];
    v[HID + tid] = db * rs * g[HID + tid] + be[HID + tid];
    __syncthreads();
    if (tid < NCLS) {
        float a = hb[tid];
        const float* wr = hw + (size_t)tid * H2;
#pragma unroll 4
        for (int k = 0; k < H2; k += 4) {
            float4 wv = *(const float4*)(wr + k);
            a = fmaf(v[k], wv.x, fmaf(v[k + 1], wv.y, fmaf(v[k + 2], wv.z, fmaf(v[k + 3], wv.w, a))));
        }
        out[(size_t)b * NCLS + tid] = a;
    }
}

// ---------------- host ----------------
extern "C" void kernel_launch(void* const* d_in, const int* in_sizes, int n_in,
                              void* d_out, int out_size, void* d_ws, size_t ws_size,
                              hipStream_t stream)
{
    const float* x     = (const float*)d_in[0];
    const float* wih0f = (const float*)d_in[1];
    const float* whh0f = (const float*)d_in[2];
    const float* bih0f = (const float*)d_in[3];
    const float* bhh0f = (const float*)d_in[4];
    const float* wih0b = (const float*)d_in[5];
    const float* whh0b = (const float*)d_in[6];
    const float* bih0b = (const float*)d_in[7];
    const float* bhh0b = (const float*)d_in[8];
    const float* wih1f = (const float*)d_in[9];
    const float* whh1f = (const float*)d_in[10];
    const float* bih1f = (const float*)d_in[11];
    const float* bhh1f = (const float*)d_in[12];
    const float* wih1b = (const float*)d_in[13];
    const float* whh1b = (const float*)d_in[14];
    const float* bih1b = (const float*)d_in[15];
    const float* bhh1b = (const float*)d_in[16];
    const float* lng   = (const float*)d_in[17];
    const float* lnb   = (const float*)d_in[18];
    const float* hw    = (const float*)d_in[19];
    const float* hbb   = (const float*)d_in[20];

    char* wsb = (char*)d_ws;
    size_t off = 0;
    auto alloc = [&](size_t bytes) -> void* {
        void* p = (void*)(wsb + off);
        off += (bytes + 255) & ~(size_t)255;
        return p;
    };
    unsigned* bar = (unsigned*)alloc(32 * 64 * sizeof(unsigned));        // 8 KB
    float* hbufA  = (float*)alloc((size_t)2 * 2 * B_SZ * HID * 4);       // 512 KB
    float* hbufB  = (float*)alloc((size_t)2 * B_SZ * HID * 4);           // 256 KB
    size_t zspan = off;                                                  // bar + h-state
    float* h2b = (float*)alloc((size_t)B_SZ * HID * 4);                  // 128 KB
    float* h1  = (float*)alloc((size_t)B_SZ * T_SZ * H2 * 4);            // 64 MB

    hipMemsetAsync(d_ws, 0, zspan, stream);  // bar + h0 state (re-run per replay)

    l0_scan<<<dim3(256), dim3(256), 0, stream>>>(
        x, wih0f, bih0f, whh0f, bhh0f, wih0b, bih0b, whh0b, bhh0b, hbufA, h1, bar);

    hipMemsetAsync(bar, 0, 32 * 64 * sizeof(unsigned), stream);  // reset counters for L1
    l1r_laststep<<<dim3(128), dim3(256), 0, stream>>>(h1, wih1b, bih1b, bhh1b, h2b);

    l1_scan<<<dim3(256), dim3(256), 0, stream>>>(
        h1, wih1f, bih1f, whh1f, bhh1f, hbufB, bar);

    // L1-fwd final h lands in parity 0 (t=255 writes (255+1)&1 == 0)
    ln_head<<<dim3(B_SZ), dim3(256), 0, stream>>>(hbufB, h2b, lng, lnb, hw, hbb, (float*)d_out);
}

// Round 7
// 3994.389 us; speedup vs baseline: 2.7438x; 1.2608x over previous
//
#include <hip/hip_runtime.h>
#include <math.h>

#define B_SZ 128
#define T_SZ 256
#define DIN  128
#define HID  256
#define H2   512
#define NCLS 250

typedef float f32x4 __attribute__((ext_vector_type(4)));

// ---- UC (device-coherent, L2-bypass) vector ops: coalesced 16B transactions.
// waitcnt folded into the load block => outputs valid on exit (no rule-18 hazard).
__device__ __forceinline__ void uc_load_2x4(const float* p0, const float* p1,
                                            f32x4& a, f32x4& b) {
    asm volatile("global_load_dwordx4 %0, %2, off sc0 sc1\n\t"
                 "global_load_dwordx4 %1, %3, off sc0 sc1\n\t"
                 "s_waitcnt vmcnt(0)"
                 : "=&v"(a), "=&v"(b)
                 : "v"(p0), "v"(p1)
                 : "memory");
}
__device__ __forceinline__ void uc_load_4x4(const float* p0, const float* p1,
                                            const float* p2, const float* p3,
                                            f32x4& a, f32x4& b, f32x4& c, f32x4& d) {
    asm volatile("global_load_dwordx4 %0, %4, off sc0 sc1\n\t"
                 "global_load_dwordx4 %1, %5, off sc0 sc1\n\t"
                 "global_load_dwordx4 %2, %6, off sc0 sc1\n\t"
                 "global_load_dwordx4 %3, %7, off sc0 sc1\n\t"
                 "s_waitcnt vmcnt(0)"
                 : "=&v"(a), "=&v"(b), "=&v"(c), "=&v"(d)
                 : "v"(p0), "v"(p1), "v"(p2), "v"(p3)
                 : "memory");
}
__device__ __forceinline__ void uc_store4(float* p, f32x4 v) {
    asm volatile("global_store_dwordx4 %0, %1, off sc0 sc1"
                 :: "v"(p), "v"(v) : "memory");
}

// ---- flag barrier: one UC store per WG, one 64B polled load per group.
__device__ __forceinline__ void flag_signal(unsigned* fl_self, unsigned v) {
    __hip_atomic_store(fl_self, v, __ATOMIC_RELAXED, __HIP_MEMORY_SCOPE_AGENT);
}
__device__ __forceinline__ void flag_wait(const unsigned* fl, unsigned target) {
    // wave 0 only; lanes poll flags[lane&15] (one 64B line -> one transaction)
    unsigned v;
    do {
        v = __hip_atomic_load(fl + (threadIdx.x & 15),
                              __ATOMIC_RELAXED, __HIP_MEMORY_SCOPE_AGENT);
    } while (!__all((int)(v >= target)));
}

#define ACC4(A, Wp, v) \
    A = fmaf((v).x, (Wp)[0], A); A = fmaf((v).y, (Wp)[1], A); \
    A = fmaf((v).z, (Wp)[2], A); A = fmaf((v).w, (Wp)[3], A)

// XCD-pinned group decode (perf-only heuristic: wg%8 == XCD on MI355X).
// 256 WGs -> 16 groups of 16, each group entirely on one XCD (2 groups/XCD).
__device__ __forceinline__ void group_decode(int wg, int& g, int& member) {
    const int x = wg & 7, s = wg >> 3;
    member = s & 15;
    g = x * 2 + (s >> 4);
}

// ---------------- L0: both dirs, fused x-GEMM, persistent scan --------------
// 16 groups: g = dir*8 + bt (16-row b-tile). member = hct (16 cols).
__global__ __launch_bounds__(256, 1) void l0_scan(
    const float* __restrict__ x,
    const float* __restrict__ wihf, const float* __restrict__ bihf,
    const float* __restrict__ whhf, const float* __restrict__ bhhf,
    const float* __restrict__ wihb, const float* __restrict__ bihb,
    const float* __restrict__ whhb, const float* __restrict__ bhhb,
    float* __restrict__ hbuf,   // [2 dir][2 par][B][HID]
    float* __restrict__ h1,     // [B][T][512]
    unsigned* __restrict__ bar)
{
    __shared__ float hlds[16][256];
    __shared__ float xlds[2][16][128];
    __shared__ float hst[16][16];
    const int tid = threadIdx.x;
    int g, member;
    group_decode(blockIdx.x, g, member);
    const int dir = g >> 3;
    const int b0  = (g & 7) * 16;
    const int hct = member;
    const int hc = tid >> 4, ks = tid & 15, ks4 = ks * 4;
    const int hcg = hct * 16 + hc;
    unsigned* fl = bar + g * 16;

    const float* wih = dir ? wihb : wihf;
    const float* bih = dir ? bihb : bihf;
    const float* whh = dir ? whhb : whhf;
    const float* bhh = dir ? bhhb : bhhf;

    float Wr[3][16], Wx[3][8];
#pragma unroll
    for (int gg = 0; gg < 3; ++gg) {
#pragma unroll
        for (int j = 0; j < 4; ++j) {
            float4 wv = *(const float4*)(whh + (size_t)(gg * HID + hcg) * HID + j * 64 + ks4);
            Wr[gg][4 * j] = wv.x; Wr[gg][4 * j + 1] = wv.y; Wr[gg][4 * j + 2] = wv.z; Wr[gg][4 * j + 3] = wv.w;
        }
#pragma unroll
        for (int j = 0; j < 2; ++j) {
            float4 wv = *(const float4*)(wih + (size_t)(gg * HID + hcg) * DIN + j * 64 + ks4);
            Wx[gg][4 * j] = wv.x; Wx[gg][4 * j + 1] = wv.y; Wx[gg][4 * j + 2] = wv.z; Wx[gg][4 * j + 3] = wv.w;
        }
    }
    const float sbr = bih[hcg] + bhh[hcg];
    const float sbz = bih[HID + hcg] + bhh[HID + hcg];
    const float bxn = bih[2 * HID + hcg];
    const float bhn = bhh[2 * HID + hcg];

    float* hb = hbuf + (size_t)dir * 2 * B_SZ * HID;
    const int r8 = tid >> 5, c32 = (tid & 31) * 4;   // x-staging map
    const int rq = tid >> 6, seg = tid & 63;         // h-load map (4 rows each)

    // ---- prologue: stage x(t=0), prefetch x(t=1), compute xsum(0)
    float4 xp[2];
    {
        const int tg0 = dir ? (T_SZ - 1) : 0;
#pragma unroll
        for (int p = 0; p < 2; ++p)
            xp[p] = *(const float4*)(x + ((size_t)(b0 + p * 8 + r8) * T_SZ + tg0) * DIN + c32);
#pragma unroll
        for (int p = 0; p < 2; ++p)
            *(float4*)&xlds[0][p * 8 + r8][c32] = xp[p];
    }
    __syncthreads();
    {
        const int tg1 = dir ? (T_SZ - 2) : 1;
#pragma unroll
        for (int p = 0; p < 2; ++p)
            xp[p] = *(const float4*)(x + ((size_t)(b0 + p * 8 + r8) * T_SZ + tg1) * DIN + c32);
    }
    float xsr[16], xsz[16], xsn[16];
#pragma unroll
    for (int b = 0; b < 16; ++b) { xsr[b] = 0.f; xsz[b] = 0.f; xsn[b] = 0.f; }
#pragma unroll
    for (int b = 0; b < 16; ++b)
#pragma unroll
        for (int j = 0; j < 2; ++j) {
            float4 xv = *(const float4*)&xlds[0][b][j * 64 + ks4];
            ACC4(xsr[b], &Wx[0][4 * j], xv);
            ACC4(xsz[b], &Wx[1][4 * j], xv);
            ACC4(xsn[b], &Wx[2][4 * j], xv);
        }
#pragma unroll
    for (int m = 1; m <= 8; m <<= 1)
#pragma unroll
        for (int b = 0; b < 16; ++b) {
            xsr[b] += __shfl_xor(xsr[b], m, 64);
            xsz[b] += __shfl_xor(xsz[b], m, 64);
            xsn[b] += __shfl_xor(xsn[b], m, 64);
        }

    for (int t = 0; t < T_SZ; ++t) {
        const int tg = dir ? (T_SZ - 1 - t) : t;
        const float* hprev = hb + (size_t)(t & 1) * B_SZ * HID;
        float* hnext       = hb + (size_t)((t + 1) & 1) * B_SZ * HID;

        if (t) { if (tid < 64) flag_wait(fl, (unsigned)t); __syncthreads(); }

        {   // UC h tile load: 4 rows x 4 cols per thread, 16B transactions
            f32x4 a, b, c, d;
            const float* base = hprev + (size_t)b0 * HID + seg * 4;
            uc_load_4x4(base + (size_t)(rq * 4 + 0) * HID, base + (size_t)(rq * 4 + 1) * HID,
                        base + (size_t)(rq * 4 + 2) * HID, base + (size_t)(rq * 4 + 3) * HID,
                        a, b, c, d);
            *(f32x4*)&hlds[rq * 4 + 0][seg * 4] = a;
            *(f32x4*)&hlds[rq * 4 + 1][seg * 4] = b;
            *(f32x4*)&hlds[rq * 4 + 2][seg * 4] = c;
            *(f32x4*)&hlds[rq * 4 + 3][seg * 4] = d;
        }
#pragma unroll
        for (int p = 0; p < 2; ++p)      // stage x(t+1)
            *(float4*)&xlds[(t + 1) & 1][p * 8 + r8][c32] = xp[p];
        __syncthreads();

        {   // prefetch x(t+2)
            const int tn  = (t + 2 < T_SZ) ? (t + 2) : (T_SZ - 1);
            const int tgn = dir ? (T_SZ - 1 - tn) : tn;
#pragma unroll
            for (int p = 0; p < 2; ++p)
                xp[p] = *(const float4*)(x + ((size_t)(b0 + p * 8 + r8) * T_SZ + tgn) * DIN + c32);
        }

        // h-part only (x-part was shadowed)
        float aR[16], aZ[16], aH[16];
#pragma unroll
        for (int b = 0; b < 16; ++b) { aR[b] = 0.f; aZ[b] = 0.f; aH[b] = 0.f; }
#pragma unroll
        for (int b = 0; b < 16; ++b)
#pragma unroll
            for (int j = 0; j < 4; ++j) {
                float4 hv4 = *(const float4*)&hlds[b][j * 64 + ks4];
                ACC4(aR[b], &Wr[0][4 * j], hv4);
                ACC4(aZ[b], &Wr[1][4 * j], hv4);
                ACC4(aH[b], &Wr[2][4 * j], hv4);
            }
#pragma unroll
        for (int m = 1; m <= 8; m <<= 1)
#pragma unroll
            for (int b = 0; b < 16; ++b) {
                aR[b] += __shfl_xor(aR[b], m, 64);
                aZ[b] += __shfl_xor(aZ[b], m, 64);
                aH[b] += __shfl_xor(aH[b], m, 64);
            }

        {   // lane ks owns batch row b0+ks
            float sr = 0.f, sz = 0.f, sh = 0.f, xr = 0.f, xz = 0.f, xn = 0.f;
#pragma unroll
            for (int b = 0; b < 16; ++b)
                if (b == ks) { sr = aR[b]; sz = aZ[b]; sh = aH[b];
                               xr = xsr[b]; xz = xsz[b]; xn = xsn[b]; }
            const float hp = hlds[ks][hcg];
            const float r = 1.f / (1.f + expf(-(sr + xr + sbr)));
            const float z = 1.f / (1.f + expf(-(sz + xz + sbz)));
            const float n = tanhf(xn + bxn + r * (sh + bhn));
            hst[ks][hc] = (1.f - z) * n + z * hp;
        }
        __syncthreads();
        f32x4 hd;
        const int sr_ = tid >> 2, sc_ = (tid & 3) * 4;
        if (tid < 64) {   // UC coalesced h-state store (64 x 16B)
            hd = *(const f32x4*)&hst[sr_][sc_];
            uc_store4(hnext + (size_t)(b0 + sr_) * HID + hct * 16 + sc_, hd);
        }
        __syncthreads();  // vmcnt(0) drain of UC stores
        if (tid == 0) flag_signal(fl + member, (unsigned)(t + 1));

        // ---- shadow work (off critical path): h1 store + x-part for t+1
        if (tid < 64)
            *(f32x4*)(h1 + ((size_t)(b0 + sr_) * T_SZ + tg) * H2 + dir * HID + hct * 16 + sc_) = hd;
#pragma unroll
        for (int b = 0; b < 16; ++b) { xsr[b] = 0.f; xsz[b] = 0.f; xsn[b] = 0.f; }
#pragma unroll
        for (int b = 0; b < 16; ++b)
#pragma unroll
            for (int j = 0; j < 2; ++j) {
                float4 xv = *(const float4*)&xlds[(t + 1) & 1][b][j * 64 + ks4];
                ACC4(xsr[b], &Wx[0][4 * j], xv);
                ACC4(xsz[b], &Wx[1][4 * j], xv);
                ACC4(xsn[b], &Wx[2][4 * j], xv);
            }
#pragma unroll
        for (int m = 1; m <= 8; m <<= 1)
#pragma unroll
            for (int b = 0; b < 16; ++b) {
                xsr[b] += __shfl_xor(xsr[b], m, 64);
                xsz[b] += __shfl_xor(xsz[b], m, 64);
                xsn[b] += __shfl_xor(xsn[b], m, 64);
            }
    }
}

// ---------------- L1 forward, fused x-GEMM (x = h1 rows, Din=512) -----------
// 16 groups: g = bt (8-row b-tile). member = hct.
__global__ __launch_bounds__(256, 1) void l1_scan(
    const float* __restrict__ h1,
    const float* __restrict__ wih, const float* __restrict__ bih,
    const float* __restrict__ whh, const float* __restrict__ bhh,
    float* __restrict__ hbuf,   // [2 par][B][HID]
    unsigned* __restrict__ bar)
{
    __shared__ float hlds[8][256];
    __shared__ float xlds[2][8][512];
    __shared__ float hst[8][16];
    const int tid = threadIdx.x;
    int g, member;
    group_decode(blockIdx.x, g, member);
    const int b0  = g * 8;
    const int hct = member;
    const int hc = tid >> 4, ks = tid & 15, ks4 = ks * 4;
    const int hcg = hct * 16 + hc;
    unsigned* fl = bar + g * 16;

    float Wr[3][16], Wx[3][32];
#pragma unroll
    for (int gg = 0; gg < 3; ++gg) {
#pragma unroll
        for (int j = 0; j < 4; ++j) {
            float4 wv = *(const float4*)(whh + (size_t)(gg * HID + hcg) * HID + j * 64 + ks4);
            Wr[gg][4 * j] = wv.x; Wr[gg][4 * j + 1] = wv.y; Wr[gg][4 * j + 2] = wv.z; Wr[gg][4 * j + 3] = wv.w;
        }
#pragma unroll
        for (int j = 0; j < 8; ++j) {
            float4 wv = *(const float4*)(wih + (size_t)(gg * HID + hcg) * H2 + j * 64 + ks4);
            Wx[gg][4 * j] = wv.x; Wx[gg][4 * j + 1] = wv.y; Wx[gg][4 * j + 2] = wv.z; Wx[gg][4 * j + 3] = wv.w;
        }
    }
    const float sbr = bih[hcg] + bhh[hcg];
    const float sbz = bih[HID + hcg] + bhh[HID + hcg];
    const float bxn = bih[2 * HID + hcg];
    const float bhn = bhh[2 * HID + hcg];

    const int r8 = tid >> 5, c32 = (tid & 31) * 4;   // x-staging map
    const int rq = tid >> 6, seg = tid & 63;         // h-load map (2 rows each)

    float4 xp[4];
    {
        const float* xsrc = h1 + ((size_t)(b0 + r8) * T_SZ + 0) * H2;
#pragma unroll
        for (int p = 0; p < 4; ++p) xp[p] = *(const float4*)(xsrc + p * 128 + c32);
#pragma unroll
        for (int p = 0; p < 4; ++p) *(float4*)&xlds[0][r8][p * 128 + c32] = xp[p];
    }
    __syncthreads();
    {
        const float* xsrc = h1 + ((size_t)(b0 + r8) * T_SZ + 1) * H2;
#pragma unroll
        for (int p = 0; p < 4; ++p) xp[p] = *(const float4*)(xsrc + p * 128 + c32);
    }
    float xsr[8], xsz[8], xsn[8];
#pragma unroll
    for (int b = 0; b < 8; ++b) { xsr[b] = 0.f; xsz[b] = 0.f; xsn[b] = 0.f; }
#pragma unroll
    for (int b = 0; b < 8; ++b)
#pragma unroll
        for (int j = 0; j < 8; ++j) {
            float4 xv = *(const float4*)&xlds[0][b][j * 64 + ks4];
            ACC4(xsr[b], &Wx[0][4 * j], xv);
            ACC4(xsz[b], &Wx[1][4 * j], xv);
            ACC4(xsn[b], &Wx[2][4 * j], xv);
        }
#pragma unroll
    for (int m = 1; m <= 8; m <<= 1)
#pragma unroll
        for (int b = 0; b < 8; ++b) {
            xsr[b] += __shfl_xor(xsr[b], m, 64);
            xsz[b] += __shfl_xor(xsz[b], m, 64);
            xsn[b] += __shfl_xor(xsn[b], m, 64);
        }

    for (int t = 0; t < T_SZ; ++t) {
        const float* hprev = hbuf + (size_t)(t & 1) * B_SZ * HID;
        float* hnext       = hbuf + (size_t)((t + 1) & 1) * B_SZ * HID;

        if (t) { if (tid < 64) flag_wait(fl, (unsigned)t); __syncthreads(); }

        {   // UC h tile load: 2 rows x 4 cols per thread
            f32x4 a, b;
            const float* base = hprev + (size_t)b0 * HID + seg * 4;
            uc_load_2x4(base + (size_t)(rq * 2 + 0) * HID, base + (size_t)(rq * 2 + 1) * HID, a, b);
            *(f32x4*)&hlds[rq * 2 + 0][seg * 4] = a;
            *(f32x4*)&hlds[rq * 2 + 1][seg * 4] = b;
        }
#pragma unroll
        for (int p = 0; p < 4; ++p)
            *(float4*)&xlds[(t + 1) & 1][r8][p * 128 + c32] = xp[p];
        __syncthreads();

        {   // prefetch x(t+2) from h1 (L2-local thanks to XCD pinning)
            const int tn = (t + 2 < T_SZ) ? (t + 2) : (T_SZ - 1);
            const float* xsrc = h1 + ((size_t)(b0 + r8) * T_SZ + tn) * H2;
#pragma unroll
            for (int p = 0; p < 4; ++p) xp[p] = *(const float4*)(xsrc + p * 128 + c32);
        }

        float aR[8], aZ[8], aH[8];
#pragma unroll
        for (int b = 0; b < 8; ++b) { aR[b] = 0.f; aZ[b] = 0.f; aH[b] = 0.f; }
#pragma unroll
        for (int b = 0; b < 8; ++b)
#pragma unroll
            for (int j = 0; j < 4; ++j) {
                float4 hv4 = *(const float4*)&hlds[b][j * 64 + ks4];
                ACC4(aR[b], &Wr[0][4 * j], hv4);
                ACC4(aZ[b], &Wr[1][4 * j], hv4);
                ACC4(aH[b], &Wr[2][4 * j], hv4);
            }
#pragma unroll
        for (int m = 1; m <= 8; m <<= 1)
#pragma unroll
            for (int b = 0; b < 8; ++b) {
                aR[b] += __shfl_xor(aR[b], m, 64);
                aZ[b] += __shfl_xor(aZ[b], m, 64);
                aH[b] += __shfl_xor(aH[b], m, 64);
            }

        if (ks < 8) {
            float sr = 0.f, sz = 0.f, sh = 0.f, xr = 0.f, xz = 0.f, xn = 0.f;
#pragma unroll
            for (int b = 0; b < 8; ++b)
                if (b == ks) { sr = aR[b]; sz = aZ[b]; sh = aH[b];
                               xr = xsr[b]; xz = xsz[b]; xn = xsn[b]; }
            const float hp = hlds[ks][hcg];
            const float r = 1.f / (1.f + expf(-(sr + xr + sbr)));
            const float z = 1.f / (1.f + expf(-(sz + xz + sbz)));
            const float n = tanhf(xn + bxn + r * (sh + bhn));
            hst[ks][hc] = (1.f - z) * n + z * hp;
        }
        __syncthreads();
        if (tid < 32) {   // UC coalesced h-state store (32 x 16B)
            const int sr_ = tid >> 2, sc_ = (tid & 3) * 4;
            f32x4 hd = *(const f32x4*)&hst[sr_][sc_];
            uc_store4(hnext + (size_t)(b0 + sr_) * HID + hct * 16 + sc_, hd);
        }
        __syncthreads();  // vmcnt(0) drain
        if (tid == 0) flag_signal(fl + member, (unsigned)(t + 1));

        // ---- shadow: x-part for t+1
#pragma unroll
        for (int b = 0; b < 8; ++b) { xsr[b] = 0.f; xsz[b] = 0.f; xsn[b] = 0.f; }
#pragma unroll
        for (int b = 0; b < 8; ++b)
#pragma unroll
            for (int j = 0; j < 8; ++j) {
                float4 xv = *(const float4*)&xlds[(t + 1) & 1][b][j * 64 + ks4];
                ACC4(xsr[b], &Wx[0][4 * j], xv);
                ACC4(xsz[b], &Wx[1][4 * j], xv);
                ACC4(xsn[b], &Wx[2][4 * j], xv);
            }
#pragma unroll
        for (int m = 1; m <= 8; m <<= 1)
#pragma unroll
            for (int b = 0; b < 8; ++b) {
                xsr[b] += __shfl_xor(xsr[b], m, 64);
                xsz[b] += __shfl_xor(xsz[b], m, 64);
                xsn[b] += __shfl_xor(xsn[b], m, 64);
            }
    }
}

// ---------------- L1 backward: only t=T-1 consumed -> one step from h0=0 ----
__global__ __launch_bounds__(256) void l1r_laststep(
    const float* __restrict__ h1, const float* __restrict__ wih,
    const float* __restrict__ bih, const float* __restrict__ bhh,
    float* __restrict__ h2b)
{
    const int tid = threadIdx.x;
    const int b  = (blockIdx.x >> 4) * 16 + (tid >> 4);
    const int hc = (blockIdx.x & 15) * 16 + (tid & 15);
    const float* hrow = h1 + ((size_t)b * T_SZ + (T_SZ - 1)) * H2;
    float ar = 0.f, az = 0.f, an = 0.f;
#pragma unroll 8
    for (int k = 0; k < H2; k += 4) {
        float4 hv = *(const float4*)(hrow + k);
        float4 wr = *(const float4*)(wih + (size_t)hc * H2 + k);
        float4 wz = *(const float4*)(wih + (size_t)(HID + hc) * H2 + k);
        float4 wn = *(const float4*)(wih + (size_t)(2 * HID + hc) * H2 + k);
        ar = fmaf(hv.x, wr.x, fmaf(hv.y, wr.y, fmaf(hv.z, wr.z, fmaf(hv.w, wr.w, ar))));
        az = fmaf(hv.x, wz.x, fmaf(hv.y, wz.y, fmaf(hv.z, wz.z, fmaf(hv.w, wz.w, az))));
        an = fmaf(hv.x, wn.x, fmaf(hv.y, wn.y, fmaf(hv.z, wn.z, fmaf(hv.w, wn.w, an))));
    }
    float r = 1.f / (1.f + expf(-(ar + bih[hc] + bhh[hc])));
    float z = 1.f / (1.f + expf(-(az + bih[HID + hc] + bhh[HID + hc])));
    float n = tanhf(an + bih[2 * HID + hc] + r * bhh[2 * HID + hc]);
    h2b[(size_t)b * HID + hc] = (1.f - z) * n;
}

// ---------------- LayerNorm + head ----------------
__global__ __launch_bounds__(256) void ln_head(
    const float* __restrict__ h2f, const float* __restrict__ h2b,
    const float* __restrict__ g, const float* __restrict__ be,
    const float* __restrict__ hw, const float* __restrict__ hb,
    float* __restrict__ out)
{
    __shared__ float v[H2];
    __shared__ float rbuf[8];
    const int b = blockIdx.x, tid = threadIdx.x;
    float xa = h2f[(size_t)b * HID + tid];
    float xb = h2b[(size_t)b * HID + tid];
    float s = xa + xb;
#pragma unroll
    for (int m = 32; m >= 1; m >>= 1) s += __shfl_xor(s, m, 64);
    if ((tid & 63) == 0) rbuf[tid >> 6] = s;
    __syncthreads();
    float mu = (rbuf[0] + rbuf[1] + rbuf[2] + rbuf[3]) * (1.0f / H2);
    float da = xa - mu, db = xb - mu;
    float q = da * da + db * db;
#pragma unroll
    for (int m = 32; m >= 1; m >>= 1) q += __shfl_xor(q, m, 64);
    __syncthreads();
    if ((tid & 63) == 0) rbuf[tid >> 6] = q;
    __syncthreads();
    float var = (rbuf[0] + rbuf[1] + rbuf[2] + rbuf[3]) * (1.0f / H2);
    float rs = rsqrtf(var + 1e-5f);
    v[tid]       = da * rs * g[tid] + be[tid];
    v[HID + tid] = db * rs * g[HID + tid] + be[HID + tid];
    __syncthreads();
    if (tid < NCLS) {
        float a = hb[tid];
        const float* wr = hw + (size_t)tid * H2;
#pragma unroll 4
        for (int k = 0; k < H2; k += 4) {
            float4 wv = *(const float4*)(wr + k);
            a = fmaf(v[k], wv.x, fmaf(v[k + 1], wv.y, fmaf(v[k + 2], wv.z, fmaf(v[k + 3], wv.w, a))));
        }
        out[(size_t)b * NCLS + tid] = a;
    }
}

// ---------------- host ----------------
extern "C" void kernel_launch(void* const* d_in, const int* in_sizes, int n_in,
                              void* d_out, int out_size, void* d_ws, size_t ws_size,
                              hipStream_t stream)
{
    const float* x     = (const float*)d_in[0];
    const float* wih0f = (const float*)d_in[1];
    const float* whh0f = (const float*)d_in[2];
    const float* bih0f = (const float*)d_in[3];
    const float* bhh0f = (const float*)d_in[4];
    const float* wih0b = (const float*)d_in[5];
    const float* whh0b = (const float*)d_in[6];
    const float* bih0b = (const float*)d_in[7];
    const float* bhh0b = (const float*)d_in[8];
    const float* wih1f = (const float*)d_in[9];
    const float* whh1f = (const float*)d_in[10];
    const float* bih1f = (const float*)d_in[11];
    const float* bhh1f = (const float*)d_in[12];
    const float* wih1b = (const float*)d_in[13];
    const float* whh1b = (const float*)d_in[14];
    const float* bih1b = (const float*)d_in[15];
    const float* bhh1b = (const float*)d_in[16];
    const float* lng   = (const float*)d_in[17];
    const float* lnb   = (const float*)d_in[18];
    const float* hw    = (const float*)d_in[19];
    const float* hbb   = (const float*)d_in[20];

    char* wsb = (char*)d_ws;
    size_t off = 0;
    auto alloc = [&](size_t bytes) -> void* {
        void* p = (void*)(wsb + off);
        off += (bytes + 255) & ~(size_t)255;
        return p;
    };
    unsigned* bar = (unsigned*)alloc(32 * 64 * sizeof(unsigned));        // 8 KB (flags)
    float* hbufA  = (float*)alloc((size_t)2 * 2 * B_SZ * HID * 4);       // 512 KB
    float* hbufB  = (float*)alloc((size_t)2 * B_SZ * HID * 4);           // 256 KB
    size_t zspan = off;                                                  // flags + h-state
    float* h2b = (float*)alloc((size_t)B_SZ * HID * 4);                  // 128 KB
    float* h1  = (float*)alloc((size_t)B_SZ * T_SZ * H2 * 4);            // 64 MB

    (void)hipMemsetAsync(d_ws, 0, zspan, stream);  // flags + h0 state (re-run per replay)

    l0_scan<<<dim3(256), dim3(256), 0, stream>>>(
        x, wih0f, bih0f, whh0f, bhh0f, wih0b, bih0b, whh0b, bhh0b, hbufA, h1, bar);

    (void)hipMemsetAsync(bar, 0, 32 * 64 * sizeof(unsigned), stream);  // reset flags for L1
    l1r_laststep<<<dim3(128), dim3(256), 0, stream>>>(h1, wih1b, bih1b, bhh1b, h2b);

    l1_scan<<<dim3(256), dim3(256), 0, stream>>>(
        h1, wih1f, bih1f, whh1f, bhh1f, hbufB, bar);

    // L1-fwd final h lands in parity 0 (t=255 writes (255+1)&1 == 0)
    ln_head<<<dim3(B_SZ), dim3(256), 0, stream>>>(hbufB, h2b, lng, lnb, hw, hbb, (float*)d_out);
}

// Round 9
// 3888.504 us; speedup vs baseline: 2.8185x; 1.0272x over previous
//
#include <hip/hip_runtime.h>
#include <math.h>

#define B_SZ 128
#define T_SZ 256
#define DIN  128
#define HID  256
#define H2   512
#define NCLS 250

typedef float    f32x4 __attribute__((ext_vector_type(4)));
typedef unsigned u32x4 __attribute__((ext_vector_type(4)));

// ---- device-coherent 16B ops (sc0 sc1 = proven agent/system visibility) ----
__device__ __forceinline__ void tg_load4(const unsigned* p,
                                         u32x4& a, u32x4& b, u32x4& c, u32x4& d) {
    asm volatile("global_load_dwordx4 %0, %4, off sc0 sc1\n\t"
                 "global_load_dwordx4 %1, %4, off offset:16 sc0 sc1\n\t"
                 "global_load_dwordx4 %2, %4, off offset:32 sc0 sc1\n\t"
                 "global_load_dwordx4 %3, %4, off offset:48 sc0 sc1\n\t"
                 "s_waitcnt vmcnt(0)"
                 : "=&v"(a), "=&v"(b), "=&v"(c), "=&v"(d) : "v"(p) : "memory");
}
__device__ __forceinline__ void tg_load2(const unsigned* p, u32x4& a, u32x4& b) {
    asm volatile("global_load_dwordx4 %0, %2, off sc0 sc1\n\t"
                 "global_load_dwordx4 %1, %2, off offset:16 sc0 sc1\n\t"
                 "s_waitcnt vmcnt(0)"
                 : "=&v"(a), "=&v"(b) : "v"(p) : "memory");
}
__device__ __forceinline__ void tg_store4(unsigned* p, u32x4 v) {
    asm volatile("global_store_dwordx4 %0, %1, off sc0 sc1" :: "v"(p), "v"(v) : "memory");
}

#define ACC4(A, Wp, v) \
    A = fmaf((v).x, (Wp)[0], A); A = fmaf((v).y, (Wp)[1], A); \
    A = fmaf((v).z, (Wp)[2], A); A = fmaf((v).w, (Wp)[3], A)

// XCD-pinned group decode (perf-only: wg%8==XCD; groups share an L2 for x/h1)
__device__ __forceinline__ void group_decode(int wg, int& g, int& member) {
    const int x = wg & 7, s = wg >> 3;
    member = s & 15;
    g = x * 2 + (s >> 4);
}

// ---------------- L0: both dirs, fused x-GEMM, persistent scan --------------
// 16 groups: g = dir*8 + bt (16-row b-tile). member = hct (16 cols).
// h exchange: tagged double buffer thb[2par][B][HID] (u32: fp32 with low 2
// mantissa bits = step tag). Readers poll tags; no flags, no drains.
__global__ __launch_bounds__(256, 1) void l0_scan(
    const float* __restrict__ x,
    const float* __restrict__ wihf, const float* __restrict__ bihf,
    const float* __restrict__ whhf, const float* __restrict__ bhhf,
    const float* __restrict__ wihb, const float* __restrict__ bihb,
    const float* __restrict__ whhb, const float* __restrict__ bhhb,
    unsigned* __restrict__ thb,   // [2 dir][2 par][B][HID] tagged
    float* __restrict__ h1)       // [B][T][512]
{
    __shared__ float hlds[16][256];
    __shared__ float xlds[2][16][128];
    __shared__ float hst[16][17];   // padded (write was 8-way bank conflict)
    const int tid = threadIdx.x;
    int g, member;
    group_decode(blockIdx.x, g, member);
    const int dir = g >> 3;
    const int b0  = (g & 7) * 16;
    const int hct = member;
    const int hc = tid >> 4, ks = tid & 15, ks4 = ks * 4;
    const int hcg = hct * 16 + hc;

    const float* wih = dir ? wihb : wihf;
    const float* bih = dir ? bihb : bihf;
    const float* whh = dir ? whhb : whhf;
    const float* bhh = dir ? bhhb : bhhf;

    float Wr[3][16], Wx[3][8];
#pragma unroll
    for (int gg = 0; gg < 3; ++gg) {
#pragma unroll
        for (int j = 0; j < 4; ++j) {
            float4 wv = *(const float4*)(whh + (size_t)(gg * HID + hcg) * HID + j * 64 + ks4);
            Wr[gg][4 * j] = wv.x; Wr[gg][4 * j + 1] = wv.y; Wr[gg][4 * j + 2] = wv.z; Wr[gg][4 * j + 3] = wv.w;
        }
#pragma unroll
        for (int j = 0; j < 2; ++j) {
            float4 wv = *(const float4*)(wih + (size_t)(gg * HID + hcg) * DIN + j * 64 + ks4);
            Wx[gg][4 * j] = wv.x; Wx[gg][4 * j + 1] = wv.y; Wx[gg][4 * j + 2] = wv.z; Wx[gg][4 * j + 3] = wv.w;
        }
    }
    const float sbr = bih[hcg] + bhh[hcg];
    const float sbz = bih[HID + hcg] + bhh[HID + hcg];
    const float bxn = bih[2 * HID + hcg];
    const float bhn = bhh[2 * HID + hcg];

    unsigned* hb = thb + (size_t)dir * 2 * B_SZ * HID;
    const int r8 = tid >> 5, c32 = (tid & 31) * 4;      // x-staging map
    const int prow = tid >> 4, pc0 = (tid & 15) * 16;   // h poll map (64B/thread)

    // ---- prologue: stage x(0), prefetch x(1), compute xsum(0)
    float4 xp[2];
    {
        const int tg0 = dir ? (T_SZ - 1) : 0;
#pragma unroll
        for (int p = 0; p < 2; ++p)
            xp[p] = *(const float4*)(x + ((size_t)(b0 + p * 8 + r8) * T_SZ + tg0) * DIN + c32);
#pragma unroll
        for (int p = 0; p < 2; ++p)
            *(float4*)&xlds[0][p * 8 + r8][c32] = xp[p];
    }
    __syncthreads();
    {
        const int tg1 = dir ? (T_SZ - 2) : 1;
#pragma unroll
        for (int p = 0; p < 2; ++p)
            xp[p] = *(const float4*)(x + ((size_t)(b0 + p * 8 + r8) * T_SZ + tg1) * DIN + c32);
    }
    float xsr[16], xsz[16], xsn[16];
#pragma unroll
    for (int b = 0; b < 16; ++b) { xsr[b] = 0.f; xsz[b] = 0.f; xsn[b] = 0.f; }
#pragma unroll
    for (int b = 0; b < 16; ++b)
#pragma unroll
        for (int j = 0; j < 2; ++j) {
            float4 xv = *(const float4*)&xlds[0][b][j * 64 + ks4];
            ACC4(xsr[b], &Wx[0][4 * j], xv);
            ACC4(xsz[b], &Wx[1][4 * j], xv);
            ACC4(xsn[b], &Wx[2][4 * j], xv);
        }
#pragma unroll
    for (int m = 1; m <= 8; m <<= 1)
#pragma unroll
        for (int b = 0; b < 16; ++b) {
            xsr[b] += __shfl_xor(xsr[b], m, 64);
            xsz[b] += __shfl_xor(xsz[b], m, 64);
            xsn[b] += __shfl_xor(xsn[b], m, 64);
        }

    for (int t = 0; t < T_SZ; ++t) {
        const int tg = dir ? (T_SZ - 1 - t) : t;
        const unsigned* hp_t = hb + (size_t)(t & 1) * B_SZ * HID;
        unsigned* hn_t       = hb + (size_t)((t + 1) & 1) * B_SZ * HID;
        const unsigned tgv = (unsigned)(t & 3);
        const unsigned wtv = (unsigned)((t + 1) & 3);

        // ---- per-thread tagged poll: wait for own 16 h values (one 64B span)
        {
            const unsigned* pp = hp_t + (size_t)(b0 + prow) * HID + pc0;
            u32x4 va, vb, vc, vd;
            for (;;) {
                tg_load4(pp, va, vb, vc, vd);
                unsigned m = (va.x^tgv)|(va.y^tgv)|(va.z^tgv)|(va.w^tgv)
                           | (vb.x^tgv)|(vb.y^tgv)|(vb.z^tgv)|(vb.w^tgv)
                           | (vc.x^tgv)|(vc.y^tgv)|(vc.z^tgv)|(vc.w^tgv)
                           | (vd.x^tgv)|(vd.y^tgv)|(vd.z^tgv)|(vd.w^tgv);
                if ((m & 3u) == 0u) break;
            }
            *(u32x4*)&hlds[prow][pc0 + 0]  = va;
            *(u32x4*)&hlds[prow][pc0 + 4]  = vb;
            *(u32x4*)&hlds[prow][pc0 + 8]  = vc;
            *(u32x4*)&hlds[prow][pc0 + 12] = vd;
        }
#pragma unroll
        for (int p = 0; p < 2; ++p)      // stage x(t+1)
            *(float4*)&xlds[(t + 1) & 1][p * 8 + r8][c32] = xp[p];
        __syncthreads();                 // SYNC1: hlds + xlds ready

        {   // prefetch x(t+2)
            const int tn  = (t + 2 < T_SZ) ? (t + 2) : (T_SZ - 1);
            const int tgn = dir ? (T_SZ - 1 - tn) : tn;
#pragma unroll
            for (int p = 0; p < 2; ++p)
                xp[p] = *(const float4*)(x + ((size_t)(b0 + p * 8 + r8) * T_SZ + tgn) * DIN + c32);
        }

        // h-part (x-part was shadowed)
        float aR[16], aZ[16], aH[16];
#pragma unroll
        for (int b = 0; b < 16; ++b) { aR[b] = 0.f; aZ[b] = 0.f; aH[b] = 0.f; }
#pragma unroll
        for (int b = 0; b < 16; ++b)
#pragma unroll
            for (int j = 0; j < 4; ++j) {
                float4 hv4 = *(const float4*)&hlds[b][j * 64 + ks4];
                ACC4(aR[b], &Wr[0][4 * j], hv4);
                ACC4(aZ[b], &Wr[1][4 * j], hv4);
                ACC4(aH[b], &Wr[2][4 * j], hv4);
            }
#pragma unroll
        for (int m = 1; m <= 8; m <<= 1)
#pragma unroll
            for (int b = 0; b < 16; ++b) {
                aR[b] += __shfl_xor(aR[b], m, 64);
                aZ[b] += __shfl_xor(aZ[b], m, 64);
                aH[b] += __shfl_xor(aH[b], m, 64);
            }

        {   // lane ks owns batch row b0+ks
            float sr = 0.f, sz = 0.f, sh = 0.f, xr = 0.f, xz = 0.f, xn = 0.f;
#pragma unroll
            for (int b = 0; b < 16; ++b)
                if (b == ks) { sr = aR[b]; sz = aZ[b]; sh = aH[b];
                               xr = xsr[b]; xz = xsz[b]; xn = xsn[b]; }
            const float hp = hlds[ks][hcg];
            const float r = 1.f / (1.f + expf(-(sr + xr + sbr)));
            const float z = 1.f / (1.f + expf(-(sz + xz + sbz)));
            const float n = tanhf(xn + bxn + r * (sh + bhn));
            hst[ks][hc] = (1.f - z) * n + z * hp;
        }
        __syncthreads();                 // SYNC2: hst ready; all hlds reads done
        if (tid < 64) {                  // pack tagged h-state + h1 store
            const int sr_ = tid >> 2, sc_ = (tid & 3) * 4;
            float4 hv4 = *(const float4*)&hst[sr_][sc_];
            u32x4 w;
            w.x = (__float_as_uint(hv4.x) & ~3u) | wtv;
            w.y = (__float_as_uint(hv4.y) & ~3u) | wtv;
            w.z = (__float_as_uint(hv4.z) & ~3u) | wtv;
            w.w = (__float_as_uint(hv4.w) & ~3u) | wtv;
            tg_store4(hn_t + (size_t)(b0 + sr_) * HID + hct * 16 + sc_, w);
            *(float4*)(h1 + ((size_t)(b0 + sr_) * T_SZ + tg) * H2 + dir * HID + hct * 16 + sc_) = hv4;
        }

        // ---- shadow: x-part for t+1 (hides under other members' stores)
#pragma unroll
        for (int b = 0; b < 16; ++b) { xsr[b] = 0.f; xsz[b] = 0.f; xsn[b] = 0.f; }
#pragma unroll
        for (int b = 0; b < 16; ++b)
#pragma unroll
            for (int j = 0; j < 2; ++j) {
                float4 xv = *(const float4*)&xlds[(t + 1) & 1][b][j * 64 + ks4];
                ACC4(xsr[b], &Wx[0][4 * j], xv);
                ACC4(xsz[b], &Wx[1][4 * j], xv);
                ACC4(xsn[b], &Wx[2][4 * j], xv);
            }
#pragma unroll
        for (int m = 1; m <= 8; m <<= 1)
#pragma unroll
            for (int b = 0; b < 16; ++b) {
                xsr[b] += __shfl_xor(xsr[b], m, 64);
                xsz[b] += __shfl_xor(xsz[b], m, 64);
                xsn[b] += __shfl_xor(xsn[b], m, 64);
            }
    }
}

// ---------------- L1 forward, fused x-GEMM (x = h1 rows, Din=512) -----------
// 16 groups: g = bt (8-row b-tile). member = hct.
__global__ __launch_bounds__(256, 1) void l1_scan(
    const float* __restrict__ h1,
    const float* __restrict__ wih, const float* __restrict__ bih,
    const float* __restrict__ whh, const float* __restrict__ bhh,
    unsigned* __restrict__ thb)   // [2 par][B][HID] tagged
{
    __shared__ float hlds[8][256];
    __shared__ float xlds[2][8][512];
    __shared__ float hst[8][17];    // padded
    const int tid = threadIdx.x;
    int g, member;
    group_decode(blockIdx.x, g, member);
    const int b0  = g * 8;
    const int hct = member;
    const int hc = tid >> 4, ks = tid & 15, ks4 = ks * 4;
    const int hcg = hct * 16 + hc;

    float Wr[3][16], Wx[3][32];
#pragma unroll
    for (int gg = 0; gg < 3; ++gg) {
#pragma unroll
        for (int j = 0; j < 4; ++j) {
            float4 wv = *(const float4*)(whh + (size_t)(gg * HID + hcg) * HID + j * 64 + ks4);
            Wr[gg][4 * j] = wv.x; Wr[gg][4 * j + 1] = wv.y; Wr[gg][4 * j + 2] = wv.z; Wr[gg][4 * j + 3] = wv.w;
        }
#pragma unroll
        for (int j = 0; j < 8; ++j) {
            float4 wv = *(const float4*)(wih + (size_t)(gg * HID + hcg) * H2 + j * 64 + ks4);
            Wx[gg][4 * j] = wv.x; Wx[gg][4 * j + 1] = wv.y; Wx[gg][4 * j + 2] = wv.z; Wx[gg][4 * j + 3] = wv.w;
        }
    }
    const float sbr = bih[hcg] + bhh[hcg];
    const float sbz = bih[HID + hcg] + bhh[HID + hcg];
    const float bxn = bih[2 * HID + hcg];
    const float bhn = bhh[2 * HID + hcg];

    const int r8 = tid >> 5, c32 = (tid & 31) * 4;      // x-staging map
    const int prow = tid >> 5, pc0 = (tid & 31) * 8;    // h poll map (32B/thread)

    float4 xp[4];
    {
        const float* xsrc = h1 + ((size_t)(b0 + r8) * T_SZ + 0) * H2;
#pragma unroll
        for (int p = 0; p < 4; ++p) xp[p] = *(const float4*)(xsrc + p * 128 + c32);
#pragma unroll
        for (int p = 0; p < 4; ++p) *(float4*)&xlds[0][r8][p * 128 + c32] = xp[p];
    }
    __syncthreads();
    {
        const float* xsrc = h1 + ((size_t)(b0 + r8) * T_SZ + 1) * H2;
#pragma unroll
        for (int p = 0; p < 4; ++p) xp[p] = *(const float4*)(xsrc + p * 128 + c32);
    }
    float xsr[8], xsz[8], xsn[8];
#pragma unroll
    for (int b = 0; b < 8; ++b) { xsr[b] = 0.f; xsz[b] = 0.f; xsn[b] = 0.f; }
#pragma unroll
    for (int b = 0; b < 8; ++b)
#pragma unroll
        for (int j = 0; j < 8; ++j) {
            float4 xv = *(const float4*)&xlds[0][b][j * 64 + ks4];
            ACC4(xsr[b], &Wx[0][4 * j], xv);
            ACC4(xsz[b], &Wx[1][4 * j], xv);
            ACC4(xsn[b], &Wx[2][4 * j], xv);
        }
#pragma unroll
    for (int m = 1; m <= 8; m <<= 1)
#pragma unroll
        for (int b = 0; b < 8; ++b) {
            xsr[b] += __shfl_xor(xsr[b], m, 64);
            xsz[b] += __shfl_xor(xsz[b], m, 64);
            xsn[b] += __shfl_xor(xsn[b], m, 64);
        }

    for (int t = 0; t < T_SZ; ++t) {
        const unsigned* hp_t = thb + (size_t)(t & 1) * B_SZ * HID;
        unsigned* hn_t       = thb + (size_t)((t + 1) & 1) * B_SZ * HID;
        const unsigned tgv = (unsigned)(t & 3);
        const unsigned wtv = (unsigned)((t + 1) & 3);

        {   // per-thread tagged poll: own 8 h values (32B span)
            const unsigned* pp = hp_t + (size_t)(b0 + prow) * HID + pc0;
            u32x4 va, vb;
            for (;;) {
                tg_load2(pp, va, vb);
                unsigned m = (va.x^tgv)|(va.y^tgv)|(va.z^tgv)|(va.w^tgv)
                           | (vb.x^tgv)|(vb.y^tgv)|(vb.z^tgv)|(vb.w^tgv);
                if ((m & 3u) == 0u) break;
            }
            *(u32x4*)&hlds[prow][pc0 + 0] = va;
            *(u32x4*)&hlds[prow][pc0 + 4] = vb;
        }
#pragma unroll
        for (int p = 0; p < 4; ++p)
            *(float4*)&xlds[(t + 1) & 1][r8][p * 128 + c32] = xp[p];
        __syncthreads();                 // SYNC1

        {   // prefetch x(t+2) from h1
            const int tn = (t + 2 < T_SZ) ? (t + 2) : (T_SZ - 1);
            const float* xsrc = h1 + ((size_t)(b0 + r8) * T_SZ + tn) * H2;
#pragma unroll
            for (int p = 0; p < 4; ++p) xp[p] = *(const float4*)(xsrc + p * 128 + c32);
        }

        float aR[8], aZ[8], aH[8];
#pragma unroll
        for (int b = 0; b < 8; ++b) { aR[b] = 0.f; aZ[b] = 0.f; aH[b] = 0.f; }
#pragma unroll
        for (int b = 0; b < 8; ++b)
#pragma unroll
            for (int j = 0; j < 4; ++j) {
                float4 hv4 = *(const float4*)&hlds[b][j * 64 + ks4];
                ACC4(aR[b], &Wr[0][4 * j], hv4);
                ACC4(aZ[b], &Wr[1][4 * j], hv4);
                ACC4(aH[b], &Wr[2][4 * j], hv4);
            }
#pragma unroll
        for (int m = 1; m <= 8; m <<= 1)
#pragma unroll
            for (int b = 0; b < 8; ++b) {
                aR[b] += __shfl_xor(aR[b], m, 64);
                aZ[b] += __shfl_xor(aZ[b], m, 64);
                aH[b] += __shfl_xor(aH[b], m, 64);
            }

        if (ks < 8) {
            float sr = 0.f, sz = 0.f, sh = 0.f, xr = 0.f, xz = 0.f, xn = 0.f;
#pragma unroll
            for (int b = 0; b < 8; ++b)
                if (b == ks) { sr = aR[b]; sz = aZ[b]; sh = aH[b];
                               xr = xsr[b]; xz = xsz[b]; xn = xsn[b]; }
            const float hp = hlds[ks][hcg];
            const float r = 1.f / (1.f + expf(-(sr + xr + sbr)));
            const float z = 1.f / (1.f + expf(-(sz + xz + sbz)));
            const float n = tanhf(xn + bxn + r * (sh + bhn));
            hst[ks][hc] = (1.f - z) * n + z * hp;
        }
        __syncthreads();                 // SYNC2
        if (tid < 32) {                  // pack tagged h-state (8 rows x 16 cols)
            const int sr_ = tid >> 2, sc_ = (tid & 3) * 4;
            float4 hv4 = *(const float4*)&hst[sr_][sc_];
            u32x4 w;
            w.x = (__float_as_uint(hv4.x) & ~3u) | wtv;
            w.y = (__float_as_uint(hv4.y) & ~3u) | wtv;
            w.z = (__float_as_uint(hv4.z) & ~3u) | wtv;
            w.w = (__float_as_uint(hv4.w) & ~3u) | wtv;
            tg_store4(hn_t + (size_t)(b0 + sr_) * HID + hct * 16 + sc_, w);
        }

        // ---- shadow: x-part for t+1
#pragma unroll
        for (int b = 0; b < 8; ++b) { xsr[b] = 0.f; xsz[b] = 0.f; xsn[b] = 0.f; }
#pragma unroll
        for (int b = 0; b < 8; ++b)
#pragma unroll
            for (int j = 0; j < 8; ++j) {
                float4 xv = *(const float4*)&xlds[(t + 1) & 1][b][j * 64 + ks4];
                ACC4(xsr[b], &Wx[0][4 * j], xv);
                ACC4(xsz[b], &Wx[1][4 * j], xv);
                ACC4(xsn[b], &Wx[2][4 * j], xv);
            }
#pragma unroll
        for (int m = 1; m <= 8; m <<= 1)
#pragma unroll
            for (int b = 0; b < 8; ++b) {
                xsr[b] += __shfl_xor(xsr[b], m, 64);
                xsz[b] += __shfl_xor(xsz[b], m, 64);
                xsn[b] += __shfl_xor(xsn[b], m, 64);
            }
    }
}

// ---------------- L1 backward: only t=T-1 consumed -> one step from h0=0 ----
__global__ __launch_bounds__(256) void l1r_laststep(
    const float* __restrict__ h1, const float* __restrict__ wih,
    const float* __restrict__ bih, const float* __restrict__ bhh,
    float* __restrict__ h2b)
{
    const int tid = threadIdx.x;
    const int b  = (blockIdx.x >> 4) * 16 + (tid >> 4);
    const int hc = (blockIdx.x & 15) * 16 + (tid & 15);
    const float* hrow = h1 + ((size_t)b * T_SZ + (T_SZ - 1)) * H2;
    float ar = 0.f, az = 0.f, an = 0.f;
#pragma unroll 8
    for (int k = 0; k < H2; k += 4) {
        float4 hv = *(const float4*)(hrow + k);
        float4 wr = *(const float4*)(wih + (size_t)hc * H2 + k);
        float4 wz = *(const float4*)(wih + (size_t)(HID + hc) * H2 + k);
        float4 wn = *(const float4*)(wih + (size_t)(2 * HID + hc) * H2 + k);
        ar = fmaf(hv.x, wr.x, fmaf(hv.y, wr.y, fmaf(hv.z, wr.z, fmaf(hv.w, wr.w, ar))));
        az = fmaf(hv.x, wz.x, fmaf(hv.y, wz.y, fmaf(hv.z, wz.z, fmaf(hv.w, wz.w, az))));
        an = fmaf(hv.x, wn.x, fmaf(hv.y, wn.y, fmaf(hv.z, wn.z, fmaf(hv.w, wn.w, an))));
    }
    float r = 1.f / (1.f + expf(-(ar + bih[hc] + bhh[hc])));
    float z = 1.f / (1.f + expf(-(az + bih[HID + hc] + bhh[HID + hc])));
    float n = tanhf(an + bih[2 * HID + hc] + r * bhh[2 * HID + hc]);
    h2b[(size_t)b * HID + hc] = (1.f - z) * n;
}

// ---------------- LayerNorm + head ----------------
__global__ __launch_bounds__(256) void ln_head(
    const float* __restrict__ h2f, const float* __restrict__ h2b,
    const float* __restrict__ g, const float* __restrict__ be,
    const float* __restrict__ hw, const float* __restrict__ hb,
    float* __restrict__ out)
{
    __shared__ float v[H2];
    __shared__ float rbuf[8];
    const int b = blockIdx.x, tid = threadIdx.x;
    float xa = h2f[(size_t)b * HID + tid];
    float xb = h2b[(size_t)b * HID + tid];
    float s = xa + xb;
#pragma unroll
    for (int m = 32; m >= 1; m >>= 1) s += __shfl_xor(s, m, 64);
    if ((tid & 63) == 0) rbuf[tid >> 6] = s;
    __syncthreads();
    float mu = (rbuf[0] + rbuf[1] + rbuf[2] + rbuf[3]) * (1.0f / H2);
    float da = xa - mu, db = xb - mu;
    float q = da * da + db * db;
#pragma unroll
    for (int m = 32; m >= 1; m >>= 1) q += __shfl_xor(q, m, 64);
    __syncthreads();
    if ((tid & 63) == 0) rbuf[tid >> 6] = q;
    __syncthreads();
    float var = (rbuf[0] + rbuf[1] + rbuf[2] + rbuf[3]) * (1.0f / H2);
    float rs = rsqrtf(var + 1e-5f);
    v[tid]       = da * rs * g[tid] + be[tid];
    v[HID + tid] = db * rs * g[HID + tid] + be[HID + tid];
    __syncthreads();
    if (tid < NCLS) {
        float a = hb[tid];
        const float* wr = hw + (size_t)tid * H2;
#pragma unroll 4
        for (int k = 0; k < H2; k += 4) {
            float4 wv = *(const float4*)(wr + k);
            a = fmaf(v[k], wv.x, fmaf(v[k + 1], wv.y, fmaf(v[k + 2], wv.z, fmaf(v[k + 3], wv.w, a))));
        }
        out[(size_t)b * NCLS + tid] = a;
    }
}

// ---------------- host ----------------
extern "C" void kernel_launch(void* const* d_in, const int* in_sizes, int n_in,
                              void* d_out, int out_size, void* d_ws, size_t ws_size,
                              hipStream_t stream)
{
    const float* x     = (const float*)d_in[0];
    const float* wih0f = (const float*)d_in[1];
    const float* whh0f = (const float*)d_in[2];
    const float* bih0f = (const float*)d_in[3];
    const float* bhh0f = (const float*)d_in[4];
    const float* wih0b = (const float*)d_in[5];
    const float* whh0b = (const float*)d_in[6];
    const float* bih0b = (const float*)d_in[7];
    const float* bhh0b = (const float*)d_in[8];
    const float* wih1f = (const float*)d_in[9];
    const float* whh1f = (const float*)d_in[10];
    const float* bih1f = (const float*)d_in[11];
    const float* bhh1f = (const float*)d_in[12];
    const float* wih1b = (const float*)d_in[13];
    const float* whh1b = (const float*)d_in[14];
    const float* bih1b = (const float*)d_in[15];
    const float* bhh1b = (const float*)d_in[16];
    const float* lng   = (const float*)d_in[17];
    const float* lnb   = (const float*)d_in[18];
    const float* hw    = (const float*)d_in[19];
    const float* hbb   = (const float*)d_in[20];

    char* wsb = (char*)d_ws;
    size_t off = 0;
    auto alloc = [&](size_t bytes) -> void* {
        void* p = (void*)(wsb + off);
        off += (bytes + 255) & ~(size_t)255;
        return p;
    };
    unsigned* thbA = (unsigned*)alloc((size_t)2 * 2 * B_SZ * HID * 4);   // 1 MB tagged
    unsigned* thbB = (unsigned*)alloc((size_t)2 * B_SZ * HID * 4);       // 512 KB tagged
    size_t zspan = off;                                                  // tagged h-state
    float* h2b = (float*)alloc((size_t)B_SZ * HID * 4);                  // 128 KB
    float* h1  = (float*)alloc((size_t)B_SZ * T_SZ * H2 * 4);            // 64 MB

    // zero tagged buffers: tag 0 == "h(0)=0 valid" (re-runs on every replay)
    (void)hipMemsetAsync(d_ws, 0, zspan, stream);

    l0_scan<<<dim3(256), dim3(256), 0, stream>>>(
        x, wih0f, bih0f, whh0f, bhh0f, wih0b, bih0b, whh0b, bhh0b, thbA, h1);

    l1r_laststep<<<dim3(128), dim3(256), 0, stream>>>(h1, wih1b, bih1b, bhh1b, h2b);

    l1_scan<<<dim3(256), dim3(256), 0, stream>>>(
        h1, wih1f, bih1f, whh1f, bhh1f, thbB);

    // L1-fwd final h lands in parity 0 (t=255 writes (255+1)&1 == 0); tags==0 bits
    ln_head<<<dim3(B_SZ), dim3(256), 0, stream>>>(
        (const float*)thbB, h2b, lng, lnb, hw, hbb, (float*)d_out);
}